// Round 12
// baseline (325.707 us; speedup 1.0000x reference)
//
#include <hip/hip_runtime.h>
#include <hip/hip_fp16.h>
#include <math.h>

#define IN_CH 128
#define HEADS 8
#define HID 16
#define OUT_CH 16
#define NEG 0.2f
#define NPB 256          // nodes per bucket (>>8)
#define MAXBUCK 400
#define AST 136          // LDS k-stride in halfs (128 + 8 pad)

__device__ __forceinline__ float lrelu(float x){ return x > 0.f ? x : NEG * x; }
__device__ __forceinline__ float elu_fast(float x){ return x > 0.f ? x : __expf(x) - 1.f; }

typedef _Float16 half8 __attribute__((ext_vector_type(8)));
typedef float    f32x4 __attribute__((ext_vector_type(4)));

// ---------------- bucketed CSR build (R8-exact) ----------------
__global__ __launch_bounds__(256) void k_bhist(const int* __restrict__ tgt, int E, int nbuck, int epb,
                                               int* __restrict__ bcnt){
    __shared__ int hist[MAXBUCK];
    int tid = threadIdx.x;
    for (int i = tid; i < nbuck; i += 256) hist[i] = 0;
    __syncthreads();
    int start = blockIdx.x * epb, end = min(start + epb, E);
    for (int e = start + tid; e < end; e += 256) atomicAdd(&hist[tgt[e] >> 8], 1);
    __syncthreads();
    for (int i = tid; i < nbuck; i += 256) if (hist[i]) atomicAdd(&bcnt[i], hist[i]);
}

__global__ void k_bscan(const int* __restrict__ bcnt, int nbuck, int E,
                        int* __restrict__ boffs, int* __restrict__ bcur){
    __shared__ int s[512];
    int t = threadIdx.x;
    int v = (t < nbuck) ? bcnt[t] : 0;
    int orig = v;
    s[t] = v; __syncthreads();
    for (int off = 1; off < 512; off <<= 1){
        int u = (t >= off) ? s[t - off] : 0;
        __syncthreads();
        v += u; s[t] = v; __syncthreads();
    }
    if (t < nbuck){ boffs[t] = v - orig; bcur[t] = v - orig; }
    if (t == 0) boffs[nbuck] = E;
}

__global__ __launch_bounds__(256) void k_bscatter(const int* __restrict__ ei, int E, int nbuck, int epb,
                                                  int* __restrict__ bcur, int2* __restrict__ ebuck){
    __shared__ int hist[MAXBUCK];
    __shared__ int base[MAXBUCK];
    int tid = threadIdx.x;
    for (int i = tid; i < nbuck; i += 256) hist[i] = 0;
    __syncthreads();
    int start = blockIdx.x * epb, end = min(start + epb, E);
    for (int e = start + tid; e < end; e += 256) atomicAdd(&hist[ei[E + e] >> 8], 1);
    __syncthreads();
    for (int i = tid; i < nbuck; i += 256){
        base[i] = hist[i] ? atomicAdd(&bcur[i], hist[i]) : 0;
        hist[i] = 0;
    }
    __syncthreads();
    for (int e = start + tid; e < end; e += 256){
        int s = ei[e], t = ei[E + e];
        int b = t >> 8;
        int r = atomicAdd(&hist[b], 1);
        ebuck[base[b] + r] = make_int2(s, t);
    }
}

__global__ __launch_bounds__(256) void k_csr(const int2* __restrict__ ebuck, const int* __restrict__ boffs,
                                             int N, int E,
                                             int* __restrict__ offs, int* __restrict__ esrc){
    __shared__ int cnt[256];
    __shared__ int sscan[256];
    __shared__ int wcur[256];
    int b = blockIdx.x;
    int tid = threadIdx.x;
    int n0 = b * 256;
    int nn = min(256, N - n0);
    cnt[tid] = (tid < nn) ? 1 : 0;
    __syncthreads();
    int e0 = boffs[b], e1 = boffs[b + 1];
    for (int e = e0 + tid; e < e1; e += 256) atomicAdd(&cnt[ebuck[e].y & 255], 1);
    __syncthreads();
    int v = cnt[tid], orig = v;
    sscan[tid] = v; __syncthreads();
    for (int off = 1; off < 256; off <<= 1){
        int u = (tid >= off) ? sscan[tid - off] : 0;
        __syncthreads();
        v += u; sscan[tid] = v; __syncthreads();
    }
    int excl = v - orig;
    int gbase = e0 + n0;
    if (tid < nn){
        offs[n0 + tid] = gbase + excl;
        esrc[gbase + excl] = n0 + tid;
    }
    wcur[tid] = excl + 1;
    __syncthreads();
    for (int e = e0 + tid; e < e1; e += 256){
        int2 p = ebuck[e];
        int r = atomicAdd(&wcur[p.y & 255], 1);
        esrc[gbase + r] = p.x;
    }
    if (b == 0 && tid == 0) offs[N] = E + N;
}

// ---------------- GEMM1 (MFMA fp16, persistent W1) + FUSED alpha1/int8-quant epilogue ----------------
// acc[t][j] at lane (m + 16*quad) holds channel t*16+m of row rbase+quad*4+j -> head t's
// 16 channels live across the quad's 16 lanes. alpha_s/alpha_d/blockmax are 4-stage
// shfl_xor{1,2,4,8} reductions; every lane then quantizes its own channel to int8.
// h1 (fp16) never touches memory; gemm1 writes h1q (int8) + asw (as1,scale) + ad1.
__global__ __launch_bounds__(256) void k_gemm1(const float* __restrict__ x, const float* __restrict__ W1,
                                               const float* __restrict__ asrc, const float* __restrict__ adst,
                                               unsigned char* __restrict__ h1q, float2* __restrict__ asw,
                                               float* __restrict__ ad1, int N, int NT){
    __shared__ _Float16 sB[128*AST];      // 34.8 KB (persistent)
    __shared__ _Float16 sA[2][64*AST];    // 2 x 17.4 KB double buffer
    int tid = threadIdx.x;
    for (int i = tid; i < 128*128; i += 256){
        int k = i >> 7, c = i & 127;
        sB[c*AST + k] = (_Float16)W1[i];
    }
    int wave = tid >> 6, lane = tid & 63;
    int m = lane & 15, quad = lane >> 4;
    int rbase = wave * 16;

    float asv[8], adv[8];
    #pragma unroll
    for (int t = 0; t < 8; ++t){
        asv[t] = asrc[t*16 + m];
        adv[t] = adst[t*16 + m];
    }

    float4 vr[8];
    int tile = blockIdx.x;
    #pragma unroll
    for (int i = 0; i < 8; ++i){
        int q = i*256 + tid;
        int r = q >> 5, seg = q & 31;
        int row = tile*64 + r;
        vr[i] = make_float4(0.f,0.f,0.f,0.f);
        if (tile < NT && row < N) vr[i] = *(const float4*)(x + (size_t)row*128 + seg*4);
    }
    int b = 0;
    for (; tile < NT; tile += gridDim.x){
        #pragma unroll
        for (int i = 0; i < 8; ++i){
            int q = i*256 + tid;
            int r = q >> 5, seg = q & 31;
            _Float16* dst = &sA[b][r*AST + seg*4];
            dst[0]=(_Float16)vr[i].x; dst[1]=(_Float16)vr[i].y;
            dst[2]=(_Float16)vr[i].z; dst[3]=(_Float16)vr[i].w;
        }
        __syncthreads();
        int tn = tile + gridDim.x;
        #pragma unroll
        for (int i = 0; i < 8; ++i){
            int q = i*256 + tid;
            int r = q >> 5, seg = q & 31;
            int row = tn*64 + r;
            vr[i] = make_float4(0.f,0.f,0.f,0.f);
            if (tn < NT && row < N) vr[i] = *(const float4*)(x + (size_t)row*128 + seg*4);
        }
        f32x4 acc[8] = {};
        #pragma unroll
        for (int kc = 0; kc < 4; ++kc){
            int kb = kc*32 + quad*8;
            half8 a = *(half8*)(&sA[b][(rbase + m)*AST + kb]);
            #pragma unroll
            for (int t = 0; t < 8; ++t){
                half8 bb = *(half8*)(&sB[(t*16 + m)*AST + kb]);
                acc[t] = __builtin_amdgcn_mfma_f32_16x16x32_f16(a, bb, acc[t], 0, 0, 0);
            }
        }
        int row0 = tile*64;
        #pragma unroll
        for (int t = 0; t < 8; ++t){
            #pragma unroll
            for (int j = 0; j < 4; ++j){
                int r = row0 + rbase + quad*4 + j;
                float v = acc[t][j];
                float ss = v * asv[t];
                float dd = v * adv[t];
                float mx = fabsf(v);
                ss += __shfl_xor(ss,1); ss += __shfl_xor(ss,2); ss += __shfl_xor(ss,4); ss += __shfl_xor(ss,8);
                dd += __shfl_xor(dd,1); dd += __shfl_xor(dd,2); dd += __shfl_xor(dd,4); dd += __shfl_xor(dd,8);
                mx = fmaxf(mx,__shfl_xor(mx,1)); mx = fmaxf(mx,__shfl_xor(mx,2));
                mx = fmaxf(mx,__shfl_xor(mx,4)); mx = fmaxf(mx,__shfl_xor(mx,8));
                mx = fmaxf(mx, 1e-12f);
                float rs = 127.f / mx;
                if (r < N){
                    int bq = (int)rintf(v*rs) + 128;
                    h1q[(size_t)r*128 + t*16 + m] = (unsigned char)bq;
                    if (m == 0){
                        asw[r*8 + t] = make_float2(ss, mx * (1.f/127.f));
                        ad1[r*8 + t] = dd;
                    }
                }
            }
        }
        b ^= 1;
    }
}

// ---------------- layer-1 aggregation: int8 gather, 2 nodes/wave, 8 lanes/edge, 16 ch/lane ----
__global__ __launch_bounds__(256) void k_agg1(const unsigned char* __restrict__ h1q, const float2* __restrict__ asw,
                                              const float* __restrict__ ad1,
                                              const int* __restrict__ offs, const int* __restrict__ esrc,
                                              const float* __restrict__ b1, __half2* __restrict__ hl2h,
                                              int nbase, int nend){
    int wv = threadIdx.x >> 6;
    int l  = threadIdx.x & 63;
    int nsub = l >> 5;
    int slot = (l >> 3) & 3;
    int c    = l & 7;
    int n = nbase + blockIdx.x*8 + wv*2 + nsub;
    bool alive = (n < nend);
    float adc = 0.f;
    int e0 = 0, deg = 0;
    if (alive){
        adc = ad1[n*8 + c];
        e0 = offs[n];
        deg = offs[n+1] - e0;
    }
    int degmax = max(deg, __shfl_xor(deg, 32));

    float acc[16] = {};
    float den = 0.f;     // sum of w
    float dq  = 0.f;     // sum of w*scale
    for (int i = 0; i < degmax; i += 8){
        int j0 = i + slot, j1 = i + 4 + slot;
        bool v0 = j0 < deg, v1 = j1 < deg;
        int iA = e0 + (v0 ? j0 : 0);
        int iB = e0 + (v1 ? j1 : 0);
        int s0 = esrc[iA], s1 = esrc[iB];
        float2 aw0 = asw[s0*8 + c];
        float2 aw1 = asw[s1*8 + c];
        uint4 q0 = *(const uint4*)(h1q + (size_t)s0*128 + c*16);
        uint4 q1 = *(const uint4*)(h1q + (size_t)s1*128 + c*16);
        float w0 = v0 ? __expf(lrelu(aw0.x + adc)) : 0.f;
        float w1 = v1 ? __expf(lrelu(aw1.x + adc)) : 0.f;
        float wq0 = w0 * aw0.y;
        float wq1 = w1 * aw1.y;
        den += w0 + w1;
        dq  += wq0 + wq1;
        const unsigned int* u0 = (const unsigned int*)&q0;
        const unsigned int* u1 = (const unsigned int*)&q1;
        #pragma unroll
        for (int d = 0; d < 4; ++d){
            unsigned int a = u0[d], b = u1[d];
            acc[4*d+0] += wq0 * (float)(a & 255u);
            acc[4*d+1] += wq0 * (float)((a >> 8) & 255u);
            acc[4*d+2] += wq0 * (float)((a >> 16) & 255u);
            acc[4*d+3] += wq0 * (float)(a >> 24);
            acc[4*d+0] += wq1 * (float)(b & 255u);
            acc[4*d+1] += wq1 * (float)((b >> 8) & 255u);
            acc[4*d+2] += wq1 * (float)((b >> 16) & 255u);
            acc[4*d+3] += wq1 * (float)(b >> 24);
        }
    }
    den += __shfl_xor(den, 8);  den += __shfl_xor(den, 16);
    dq  += __shfl_xor(dq, 8);   dq  += __shfl_xor(dq, 16);
    #pragma unroll
    for (int k = 0; k < 16; ++k){
        acc[k] += __shfl_xor(acc[k], 8);
        acc[k] += __shfl_xor(acc[k], 16);
    }
    if (!alive) return;
    float rd = 1.f / (den + 1e-16f);
    float bias128 = 128.f * dq;
    float sel0, sel1, sel2, sel3;
    {
        float a0 = (slot & 1) ? acc[4]  : acc[0];
        float b0 = (slot & 1) ? acc[12] : acc[8];
        sel0 = (slot & 2) ? b0 : a0;
        float a1 = (slot & 1) ? acc[5]  : acc[1];
        float b1v = (slot & 1) ? acc[13] : acc[9];
        sel1 = (slot & 2) ? b1v : a1;
        float a2 = (slot & 1) ? acc[6]  : acc[2];
        float b2v = (slot & 1) ? acc[14] : acc[10];
        sel2 = (slot & 2) ? b2v : a2;
        float a3 = (slot & 1) ? acc[7]  : acc[3];
        float b3v = (slot & 1) ? acc[15] : acc[11];
        sel3 = (slot & 2) ? b3v : a3;
    }
    float4 b4 = *(const float4*)(b1 + c*16 + slot*4);
    float v0 = elu_fast((sel0 - bias128)*rd + b4.x);
    float v1 = elu_fast((sel1 - bias128)*rd + b4.y);
    float v2 = elu_fast((sel2 - bias128)*rd + b4.z);
    float v3 = elu_fast((sel3 - bias128)*rd + b4.w);
    __half2 q0h = __floats2half2_rn(v0, v1);
    __half2 q1h = __floats2half2_rn(v2, v3);
    float2 ov;
    *(__half2*)&ov.x = q0h; *(__half2*)&ov.y = q1h;
    *(float2*)(hl2h + (size_t)n*64 + c*8 + slot*2) = ov;
}

// ---------------- GEMM2: h2 = hl2 @ W2 -> fp16 + fused alpha2 ----------------
#define FMA4(acc, a, b) { acc.x += (a)*(b).x; acc.y += (a)*(b).y; acc.z += (a)*(b).z; acc.w += (a)*(b).w; }

__global__ __launch_bounds__(256) void k_gemm2(const __half2* __restrict__ hl2h, const float* __restrict__ W2,
                                               const float* __restrict__ asrc2, const float* __restrict__ adst2,
                                               __half2* __restrict__ h2h, float* __restrict__ as2, float* __restrict__ ad2,
                                               int N){
    __shared__ float sX[64*132];
    __shared__ float sW2[128*16];
    int tid = threadIdx.x;
    for (int i = tid; i < 128*16; i += 256) sW2[i] = W2[i];
    int row0 = blockIdx.x * 64;
    #pragma unroll
    for (int i = 0; i < 4; ++i){
        int q = i*256 + tid;
        int r = q >> 4, seg = q & 15;
        float4 raw = make_float4(0.f,0.f,0.f,0.f);
        if (row0 + r < N) raw = ((const float4*)(hl2h + (size_t)(row0+r)*64))[seg];
        const __half2* hp = (const __half2*)&raw;
        float* dst = &sX[r*132 + seg*8];
        #pragma unroll
        for (int j = 0; j < 4; ++j){
            float2 f = __half22float2(hp[j]);
            dst[2*j] = f.x; dst[2*j+1] = f.y;
        }
    }
    __syncthreads();
    int nd = tid >> 2;
    int cq = tid & 3, c0 = cq*4;
    int n = row0 + nd;
    float4 acc = make_float4(0.f,0.f,0.f,0.f);
    #pragma unroll 4
    for (int k4 = 0; k4 < 32; ++k4){
        float4 a  = *(const float4*)(&sX[nd*132 + k4*4]);
        float4 w0 = *(const float4*)(&sW2[(k4*4+0)*16 + c0]);
        float4 w1 = *(const float4*)(&sW2[(k4*4+1)*16 + c0]);
        float4 w2 = *(const float4*)(&sW2[(k4*4+2)*16 + c0]);
        float4 w3 = *(const float4*)(&sW2[(k4*4+3)*16 + c0]);
        FMA4(acc, a.x, w0); FMA4(acc, a.y, w1); FMA4(acc, a.z, w2); FMA4(acc, a.w, w3);
    }
    float ps = acc.x*asrc2[c0] + acc.y*asrc2[c0+1] + acc.z*asrc2[c0+2] + acc.w*asrc2[c0+3];
    float pd = acc.x*adst2[c0] + acc.y*adst2[c0+1] + acc.z*adst2[c0+2] + acc.w*adst2[c0+3];
    ps += __shfl_xor(ps, 1); ps += __shfl_xor(ps, 2);
    pd += __shfl_xor(pd, 1); pd += __shfl_xor(pd, 2);
    if (n < N){
        __half2 p0 = __floats2half2_rn(acc.x, acc.y);
        __half2 p1 = __floats2half2_rn(acc.z, acc.w);
        float2 ov;
        *(__half2*)&ov.x = p0; *(__half2*)&ov.y = p1;
        *(float2*)(h2h + (size_t)n*8 + cq*2) = ov;
        if (cq == 0){ as2[n] = ps; ad2[n] = pd; }
    }
}

// ---------------- layer-2 fused aggregation (half2 gather, 8 edges in flight) -> out ----------------
__global__ __launch_bounds__(256) void k_agg2(const __half2* __restrict__ h2h, const float* __restrict__ as2v,
                                              const float* __restrict__ ad2v,
                                              const int* __restrict__ offs, const int* __restrict__ esrc,
                                              const float* __restrict__ b2, float* __restrict__ out, int N){
    int n = blockIdx.x*4 + (threadIdx.x >> 6);
    if (n >= N) return;
    int l = threadIdx.x & 63;
    int e0 = offs[n], e1 = offs[n+1];
    float ad = ad2v[n];
    int eo = l >> 3, c2 = l & 7;
    float ax = 0.f, ay = 0.f, den = 0.f;
    for (int e = e0 + eo; e < e1; e += 8){
        int s = esrc[e];
        float w = __expf(lrelu(as2v[s] + ad));
        den += w;
        float2 f = __half22float2(h2h[(size_t)s*8 + c2]);
        ax += w * f.x; ay += w * f.y;
    }
    ax += __shfl_xor(ax, 8);  ay += __shfl_xor(ay, 8);  den += __shfl_xor(den, 8);
    ax += __shfl_xor(ax, 16); ay += __shfl_xor(ay, 16); den += __shfl_xor(den, 16);
    ax += __shfl_xor(ax, 32); ay += __shfl_xor(ay, 32); den += __shfl_xor(den, 32);
    if (eo == 0){
        float rd = 1.f / (den + 1e-16f);
        float2 bb = *(const float2*)(b2 + c2*2);
        float2 o = make_float2(ax*rd + bb.x, ay*rd + bb.y);
        *(float2*)(out + (size_t)n*16 + c2*2) = o;
    }
}

extern "C" void kernel_launch(void* const* d_in, const int* in_sizes, int n_in,
                              void* d_out, int out_size, void* d_ws, size_t ws_size,
                              hipStream_t stream){
    const float* x     = (const float*)d_in[0];
    const int*   ei    = (const int*)  d_in[1];
    const float* W1    = (const float*)d_in[2];
    const float* asrc1 = (const float*)d_in[3];
    const float* adst1 = (const float*)d_in[4];
    const float* b1    = (const float*)d_in[5];
    const float* W2    = (const float*)d_in[6];
    const float* asrc2 = (const float*)d_in[7];
    const float* adst2 = (const float*)d_in[8];
    const float* b2    = (const float*)d_in[9];
    float* out = (float*)d_out;

    const int N = in_sizes[0] / IN_CH;   // 100000
    const int E = in_sizes[1] / 2;       // 1600000
    const int ETOT = E + N;
    const int NBUCK = (N + NPB - 1) / NPB;   // 391

    char* p = (char*)d_ws;
    auto alloc = [&](size_t bytes) -> char* {
        char* r = p; p += (bytes + 255) & ~(size_t)255; return r;
    };
    __half2* hl2h = (__half2*)alloc((size_t)N * 64 * 4);
    unsigned char* h1q = (unsigned char*)alloc((size_t)N * 128);
    float2* asw  = (float2*)alloc((size_t)N * 8 * 8);
    float* ad1   = (float*)alloc((size_t)N * 8 * 4);
    __half2* h2h = (__half2*)alloc((size_t)N * 8 * 4);
    float* as2   = (float*)alloc((size_t)N * 4);
    float* ad2   = (float*)alloc((size_t)N * 4);
    int*   bcnt  = (int*)  alloc((size_t)MAXBUCK * 4);
    int*   boffs = (int*)  alloc((size_t)(MAXBUCK + 1) * 4);
    int*   bcur  = (int*)  alloc((size_t)MAXBUCK * 4);
    int*   offs  = (int*)  alloc((size_t)(N + 1) * 4);
    int*   esrc  = (int*)  alloc((size_t)ETOT * 4);
    int2*  ebuck = (int2*)hl2h;   // aliases hl2h; k_csr done before k_agg1 writes it

    (void)hipMemsetAsync(bcnt, 0, (size_t)NBUCK * 4, stream);

    const int GPART = 512;
    const int epb = (E + GPART - 1) / GPART;

    k_bhist   <<<GPART, 256, 0, stream>>>(ei + E, E, NBUCK, epb, bcnt);
    k_bscan   <<<1,     512, 0, stream>>>(bcnt, NBUCK, E, boffs, bcur);
    k_bscatter<<<GPART, 256, 0, stream>>>(ei, E, NBUCK, epb, bcur, ebuck);
    k_csr     <<<NBUCK, 256, 0, stream>>>(ebuck, boffs, N, E, offs, esrc);

    const int NT = (N + 63) / 64;           // 1563 row tiles
    const int G1 = NT < 512 ? NT : 512;     // 2 blocks/CU, persistent W1
    k_gemm1  <<<G1, 256, 0, stream>>>(x, W1, asrc1, adst1, h1q, asw, ad1, N, NT);

    const int NH = ((N / 2) + 7) & ~7;   // split agg1 for profile visibility
    k_agg1 <<<(NH + 7) / 8, 256, 0, stream>>>(h1q, asw, ad1, offs, esrc, b1, hl2h, 0, NH);
    k_agg1 <<<((N - NH) + 7) / 8, 256, 0, stream>>>(h1q, asw, ad1, offs, esrc, b1, hl2h, NH, N);

    k_gemm2  <<<(N + 63) / 64, 256, 0, stream>>>(hl2h, W2, asrc2, adst2, h2h, as2, ad2, N);
    k_agg2   <<<(N + 3) / 4, 256, 0, stream>>>(h2h, as2, ad2, offs, esrc, b2, out, N);
}

// Round 13
// 310.769 us; speedup vs baseline: 1.0481x; 1.0481x over previous
//
#include <hip/hip_runtime.h>
#include <hip/hip_fp16.h>
#include <math.h>

#define IN_CH 128
#define HEADS 8
#define HID 16
#define OUT_CH 16
#define NEG 0.2f
#define NPB 256          // nodes per bucket (>>8)
#define MAXBUCK 400
#define AST 136          // LDS k-stride in halfs (128 + 8 pad)

__device__ __forceinline__ float lrelu(float x){ return x > 0.f ? x : NEG * x; }
__device__ __forceinline__ float elu_fast(float x){ return x > 0.f ? x : __expf(x) - 1.f; }

typedef _Float16 half8 __attribute__((ext_vector_type(8)));
typedef float    f32x4 __attribute__((ext_vector_type(4)));

// ---------------- bucketed CSR build (R8 structure; bhist spills per-block hist) ----------------
__global__ __launch_bounds__(256) void k_bhist(const int* __restrict__ tgt, int E, int nbuck, int epb,
                                               int* __restrict__ bcnt, int* __restrict__ pbh){
    __shared__ int hist[MAXBUCK];
    int tid = threadIdx.x;
    for (int i = tid; i < nbuck; i += 256) hist[i] = 0;
    __syncthreads();
    int start = blockIdx.x * epb, end = min(start + epb, E);
    for (int e = start + tid; e < end; e += 256) atomicAdd(&hist[tgt[e] >> 8], 1);
    __syncthreads();
    int* row = pbh + (size_t)blockIdx.x * MAXBUCK;
    for (int i = tid; i < nbuck; i += 256){
        int h = hist[i];
        row[i] = h;
        if (h) atomicAdd(&bcnt[i], h);
    }
}

__global__ void k_bscan(const int* __restrict__ bcnt, int nbuck, int E,
                        int* __restrict__ boffs, int* __restrict__ bcur){
    __shared__ int s[512];
    int t = threadIdx.x;
    int v = (t < nbuck) ? bcnt[t] : 0;
    int orig = v;
    s[t] = v; __syncthreads();
    for (int off = 1; off < 512; off <<= 1){
        int u = (t >= off) ? s[t - off] : 0;
        __syncthreads();
        v += u; s[t] = v; __syncthreads();
    }
    if (t < nbuck){ boffs[t] = v - orig; bcur[t] = v - orig; }
    if (t == 0) boffs[nbuck] = E;
}

// scatter pass reuses bhist's spilled per-block histogram (no re-histogram pass)
__global__ __launch_bounds__(256) void k_bscatter(const int* __restrict__ ei, int E, int nbuck, int epb,
                                                  const int* __restrict__ pbh,
                                                  int* __restrict__ bcur, int2* __restrict__ ebuck){
    __shared__ int hist[MAXBUCK];
    __shared__ int base[MAXBUCK];
    int tid = threadIdx.x;
    const int* row = pbh + (size_t)blockIdx.x * MAXBUCK;
    for (int i = tid; i < nbuck; i += 256){
        int h = row[i];
        base[i] = h ? atomicAdd(&bcur[i], h) : 0;
        hist[i] = 0;
    }
    __syncthreads();
    int start = blockIdx.x * epb, end = min(start + epb, E);
    for (int e = start + tid; e < end; e += 256){
        int s = ei[e], t = ei[E + e];
        int b = t >> 8;
        int r = atomicAdd(&hist[b], 1);
        ebuck[base[b] + r] = make_int2(s, t);
    }
}

__global__ __launch_bounds__(256) void k_csr(const int2* __restrict__ ebuck, const int* __restrict__ boffs,
                                             int N, int E,
                                             int* __restrict__ offs, int* __restrict__ esrc){
    __shared__ int cnt[256];
    __shared__ int sscan[256];
    __shared__ int wcur[256];
    int b = blockIdx.x;
    int tid = threadIdx.x;
    int n0 = b * 256;
    int nn = min(256, N - n0);
    cnt[tid] = (tid < nn) ? 1 : 0;
    __syncthreads();
    int e0 = boffs[b], e1 = boffs[b + 1];
    for (int e = e0 + tid; e < e1; e += 256) atomicAdd(&cnt[ebuck[e].y & 255], 1);
    __syncthreads();
    int v = cnt[tid], orig = v;
    sscan[tid] = v; __syncthreads();
    for (int off = 1; off < 256; off <<= 1){
        int u = (tid >= off) ? sscan[tid - off] : 0;
        __syncthreads();
        v += u; sscan[tid] = v; __syncthreads();
    }
    int excl = v - orig;
    int gbase = e0 + n0;
    if (tid < nn){
        offs[n0 + tid] = gbase + excl;
        esrc[gbase + excl] = n0 + tid;
    }
    wcur[tid] = excl + 1;
    __syncthreads();
    for (int e = e0 + tid; e < e1; e += 256){
        int2 p = ebuck[e];
        int r = atomicAdd(&wcur[p.y & 255], 1);
        esrc[gbase + r] = p.x;
    }
    if (b == 0 && tid == 0) offs[N] = E + N;
}

// ---------------- GEMM1 (MFMA fp16, persistent W1): h1 = x @ W1 -> fp16 [N][128] ----------------
__global__ __launch_bounds__(256) void k_gemm1(const float* __restrict__ x, const float* __restrict__ W1,
                                               __half* __restrict__ h1, int N, int NT){
    __shared__ _Float16 sB[128*AST];      // 34.8 KB (persistent)
    __shared__ _Float16 sA[2][64*AST];    // 2 x 17.4 KB double buffer
    int tid = threadIdx.x;
    for (int i = tid; i < 128*128; i += 256){
        int k = i >> 7, c = i & 127;
        sB[c*AST + k] = (_Float16)W1[i];
    }
    int wave = tid >> 6, lane = tid & 63;
    int m = lane & 15, quad = lane >> 4;
    int rbase = wave * 16;

    float4 vr[8];
    int tile = blockIdx.x;
    #pragma unroll
    for (int i = 0; i < 8; ++i){
        int q = i*256 + tid;
        int r = q >> 5, seg = q & 31;
        int row = tile*64 + r;
        vr[i] = make_float4(0.f,0.f,0.f,0.f);
        if (tile < NT && row < N) vr[i] = *(const float4*)(x + (size_t)row*128 + seg*4);
    }
    int b = 0;
    for (; tile < NT; tile += gridDim.x){
        #pragma unroll
        for (int i = 0; i < 8; ++i){
            int q = i*256 + tid;
            int r = q >> 5, seg = q & 31;
            _Float16* dst = &sA[b][r*AST + seg*4];
            dst[0]=(_Float16)vr[i].x; dst[1]=(_Float16)vr[i].y;
            dst[2]=(_Float16)vr[i].z; dst[3]=(_Float16)vr[i].w;
        }
        __syncthreads();
        int tn = tile + gridDim.x;
        #pragma unroll
        for (int i = 0; i < 8; ++i){
            int q = i*256 + tid;
            int r = q >> 5, seg = q & 31;
            int row = tn*64 + r;
            vr[i] = make_float4(0.f,0.f,0.f,0.f);
            if (tn < NT && row < N) vr[i] = *(const float4*)(x + (size_t)row*128 + seg*4);
        }
        f32x4 acc[8] = {};
        #pragma unroll
        for (int kc = 0; kc < 4; ++kc){
            int kb = kc*32 + quad*8;
            half8 a = *(half8*)(&sA[b][(rbase + m)*AST + kb]);
            #pragma unroll
            for (int t = 0; t < 8; ++t){
                half8 bb = *(half8*)(&sB[(t*16 + m)*AST + kb]);
                acc[t] = __builtin_amdgcn_mfma_f32_16x16x32_f16(a, bb, acc[t], 0, 0, 0);
            }
        }
        int row0 = tile*64;
        #pragma unroll
        for (int t = 0; t < 8; ++t){
            #pragma unroll
            for (int j = 0; j < 4; ++j){
                int r = row0 + rbase + quad*4 + j;
                if (r < N) h1[(size_t)r*128 + t*16 + m] = __float2half(acc[t][j]);
            }
        }
        b ^= 1;
    }
}

// ---------------- attention logits + per-(node,head) int8 quantization ----------------
struct H8 { __half2 v[8]; };

__global__ void k_alpha1(const __half2* __restrict__ h1h, const float* __restrict__ asrc, const float* __restrict__ adst,
                         float2* __restrict__ asw, float* __restrict__ ad1,
                         unsigned char* __restrict__ h1q, int N){
    int idx = blockIdx.x*blockDim.x + threadIdx.x;
    if (idx >= N*HEADS) return;
    int h = idx & 7;
    int n = idx >> 3;
    H8 blk = *(const H8*)(h1h + (size_t)n*64 + h*8);
    const float2* sp = (const float2*)(asrc + h*16);
    const float2* dp = (const float2*)(adst + h*16);
    float fv[16];
    float ss = 0.f, dd = 0.f;
    #pragma unroll
    for (int j = 0; j < 8; ++j){
        float2 v = __half22float2(blk.v[j]);
        fv[2*j] = v.x; fv[2*j+1] = v.y;
        float2 a = sp[j], b = dp[j];
        ss += v.x*a.x + v.y*a.y;
        dd += v.x*b.x + v.y*b.y;
    }
    float mx = 1e-12f;
    #pragma unroll
    for (int k = 0; k < 16; ++k) mx = fmaxf(mx, fabsf(fv[k]));
    float rs = 127.f / mx;
    unsigned int w[4];
    #pragma unroll
    for (int d = 0; d < 4; ++d){
        unsigned int b0 = (unsigned int)((int)rintf(fv[4*d+0]*rs) + 128);
        unsigned int b1 = (unsigned int)((int)rintf(fv[4*d+1]*rs) + 128);
        unsigned int b2 = (unsigned int)((int)rintf(fv[4*d+2]*rs) + 128);
        unsigned int b3 = (unsigned int)((int)rintf(fv[4*d+3]*rs) + 128);
        w[d] = b0 | (b1 << 8) | (b2 << 16) | (b3 << 24);
    }
    asw[idx] = make_float2(ss, mx * (1.f/127.f));
    ad1[idx] = dd;
    *(uint4*)(h1q + (size_t)idx*16) = make_uint4(w[0], w[1], w[2], w[3]);
}

// ---------------- layer-1 aggregation: int8 gather, 2 nodes/wave, 8 lanes/edge, 16 ch/lane ----
__global__ __launch_bounds__(256) void k_agg1(const unsigned char* __restrict__ h1q, const float2* __restrict__ asw,
                                              const float* __restrict__ ad1,
                                              const int* __restrict__ offs, const int* __restrict__ esrc,
                                              const float* __restrict__ b1, __half2* __restrict__ hl2h,
                                              int nbase, int nend){
    int wv = threadIdx.x >> 6;
    int l  = threadIdx.x & 63;
    int nsub = l >> 5;
    int slot = (l >> 3) & 3;
    int c    = l & 7;
    int n = nbase + blockIdx.x*8 + wv*2 + nsub;
    bool alive = (n < nend);
    float adc = 0.f;
    int e0 = 0, deg = 0;
    if (alive){
        adc = ad1[n*8 + c];
        e0 = offs[n];
        deg = offs[n+1] - e0;
    }
    int degmax = max(deg, __shfl_xor(deg, 32));

    float acc[16] = {};
    float den = 0.f;     // sum of w
    float dq  = 0.f;     // sum of w*scale
    for (int i = 0; i < degmax; i += 8){
        int j0 = i + slot, j1 = i + 4 + slot;
        bool v0 = j0 < deg, v1 = j1 < deg;
        int iA = e0 + (v0 ? j0 : 0);
        int iB = e0 + (v1 ? j1 : 0);
        int s0 = esrc[iA], s1 = esrc[iB];
        float2 aw0 = asw[s0*8 + c];
        float2 aw1 = asw[s1*8 + c];
        uint4 q0 = *(const uint4*)(h1q + (size_t)s0*128 + c*16);
        uint4 q1 = *(const uint4*)(h1q + (size_t)s1*128 + c*16);
        float w0 = v0 ? __expf(lrelu(aw0.x + adc)) : 0.f;
        float w1 = v1 ? __expf(lrelu(aw1.x + adc)) : 0.f;
        float wq0 = w0 * aw0.y;
        float wq1 = w1 * aw1.y;
        den += w0 + w1;
        dq  += wq0 + wq1;
        const unsigned int* u0 = (const unsigned int*)&q0;
        const unsigned int* u1 = (const unsigned int*)&q1;
        #pragma unroll
        for (int d = 0; d < 4; ++d){
            unsigned int a = u0[d], b = u1[d];
            acc[4*d+0] += wq0 * (float)(a & 255u);
            acc[4*d+1] += wq0 * (float)((a >> 8) & 255u);
            acc[4*d+2] += wq0 * (float)((a >> 16) & 255u);
            acc[4*d+3] += wq0 * (float)(a >> 24);
            acc[4*d+0] += wq1 * (float)(b & 255u);
            acc[4*d+1] += wq1 * (float)((b >> 8) & 255u);
            acc[4*d+2] += wq1 * (float)((b >> 16) & 255u);
            acc[4*d+3] += wq1 * (float)(b >> 24);
        }
    }
    den += __shfl_xor(den, 8);  den += __shfl_xor(den, 16);
    dq  += __shfl_xor(dq, 8);   dq  += __shfl_xor(dq, 16);
    #pragma unroll
    for (int k = 0; k < 16; ++k){
        acc[k] += __shfl_xor(acc[k], 8);
        acc[k] += __shfl_xor(acc[k], 16);
    }
    if (!alive) return;
    float rd = 1.f / (den + 1e-16f);
    float bias128 = 128.f * dq;
    float sel0, sel1, sel2, sel3;
    {
        float a0 = (slot & 1) ? acc[4]  : acc[0];
        float b0 = (slot & 1) ? acc[12] : acc[8];
        sel0 = (slot & 2) ? b0 : a0;
        float a1 = (slot & 1) ? acc[5]  : acc[1];
        float b1v = (slot & 1) ? acc[13] : acc[9];
        sel1 = (slot & 2) ? b1v : a1;
        float a2 = (slot & 1) ? acc[6]  : acc[2];
        float b2v = (slot & 1) ? acc[14] : acc[10];
        sel2 = (slot & 2) ? b2v : a2;
        float a3 = (slot & 1) ? acc[7]  : acc[3];
        float b3v = (slot & 1) ? acc[15] : acc[11];
        sel3 = (slot & 2) ? b3v : a3;
    }
    float4 b4 = *(const float4*)(b1 + c*16 + slot*4);
    float v0 = elu_fast((sel0 - bias128)*rd + b4.x);
    float v1 = elu_fast((sel1 - bias128)*rd + b4.y);
    float v2 = elu_fast((sel2 - bias128)*rd + b4.z);
    float v3 = elu_fast((sel3 - bias128)*rd + b4.w);
    __half2 q0h = __floats2half2_rn(v0, v1);
    __half2 q1h = __floats2half2_rn(v2, v3);
    float2 ov;
    *(__half2*)&ov.x = q0h; *(__half2*)&ov.y = q1h;
    *(float2*)(hl2h + (size_t)n*64 + c*8 + slot*2) = ov;
}

// ---------------- GEMM2: h2 = hl2 @ W2 -> fp16 + fused alpha2 ----------------
#define FMA4(acc, a, b) { acc.x += (a)*(b).x; acc.y += (a)*(b).y; acc.z += (a)*(b).z; acc.w += (a)*(b).w; }

__global__ __launch_bounds__(256) void k_gemm2(const __half2* __restrict__ hl2h, const float* __restrict__ W2,
                                               const float* __restrict__ asrc2, const float* __restrict__ adst2,
                                               __half2* __restrict__ h2h, float* __restrict__ as2, float* __restrict__ ad2,
                                               int N){
    __shared__ float sX[64*132];
    __shared__ float sW2[128*16];
    int tid = threadIdx.x;
    for (int i = tid; i < 128*16; i += 256) sW2[i] = W2[i];
    int row0 = blockIdx.x * 64;
    #pragma unroll
    for (int i = 0; i < 4; ++i){
        int q = i*256 + tid;
        int r = q >> 4, seg = q & 15;
        float4 raw = make_float4(0.f,0.f,0.f,0.f);
        if (row0 + r < N) raw = ((const float4*)(hl2h + (size_t)(row0+r)*64))[seg];
        const __half2* hp = (const __half2*)&raw;
        float* dst = &sX[r*132 + seg*8];
        #pragma unroll
        for (int j = 0; j < 4; ++j){
            float2 f = __half22float2(hp[j]);
            dst[2*j] = f.x; dst[2*j+1] = f.y;
        }
    }
    __syncthreads();
    int nd = tid >> 2;
    int cq = tid & 3, c0 = cq*4;
    int n = row0 + nd;
    float4 acc = make_float4(0.f,0.f,0.f,0.f);
    #pragma unroll 4
    for (int k4 = 0; k4 < 32; ++k4){
        float4 a  = *(const float4*)(&sX[nd*132 + k4*4]);
        float4 w0 = *(const float4*)(&sW2[(k4*4+0)*16 + c0]);
        float4 w1 = *(const float4*)(&sW2[(k4*4+1)*16 + c0]);
        float4 w2 = *(const float4*)(&sW2[(k4*4+2)*16 + c0]);
        float4 w3 = *(const float4*)(&sW2[(k4*4+3)*16 + c0]);
        FMA4(acc, a.x, w0); FMA4(acc, a.y, w1); FMA4(acc, a.z, w2); FMA4(acc, a.w, w3);
    }
    float ps = acc.x*asrc2[c0] + acc.y*asrc2[c0+1] + acc.z*asrc2[c0+2] + acc.w*asrc2[c0+3];
    float pd = acc.x*adst2[c0] + acc.y*adst2[c0+1] + acc.z*adst2[c0+2] + acc.w*adst2[c0+3];
    ps += __shfl_xor(ps, 1); ps += __shfl_xor(ps, 2);
    pd += __shfl_xor(pd, 1); pd += __shfl_xor(pd, 2);
    if (n < N){
        __half2 p0 = __floats2half2_rn(acc.x, acc.y);
        __half2 p1 = __floats2half2_rn(acc.z, acc.w);
        float2 ov;
        *(__half2*)&ov.x = p0; *(__half2*)&ov.y = p1;
        *(float2*)(h2h + (size_t)n*8 + cq*2) = ov;
        if (cq == 0){ as2[n] = ps; ad2[n] = pd; }
    }
}

// ---------------- layer-2 fused aggregation (half2 gather, 8 edges in flight) -> out ----------------
__global__ __launch_bounds__(256) void k_agg2(const __half2* __restrict__ h2h, const float* __restrict__ as2v,
                                              const float* __restrict__ ad2v,
                                              const int* __restrict__ offs, const int* __restrict__ esrc,
                                              const float* __restrict__ b2, float* __restrict__ out, int N){
    int n = blockIdx.x*4 + (threadIdx.x >> 6);
    if (n >= N) return;
    int l = threadIdx.x & 63;
    int e0 = offs[n], e1 = offs[n+1];
    float ad = ad2v[n];
    int eo = l >> 3, c2 = l & 7;
    float ax = 0.f, ay = 0.f, den = 0.f;
    for (int e = e0 + eo; e < e1; e += 8){
        int s = esrc[e];
        float w = __expf(lrelu(as2v[s] + ad));
        den += w;
        float2 f = __half22float2(h2h[(size_t)s*8 + c2]);
        ax += w * f.x; ay += w * f.y;
    }
    ax += __shfl_xor(ax, 8);  ay += __shfl_xor(ay, 8);  den += __shfl_xor(den, 8);
    ax += __shfl_xor(ax, 16); ay += __shfl_xor(ay, 16); den += __shfl_xor(den, 16);
    ax += __shfl_xor(ax, 32); ay += __shfl_xor(ay, 32); den += __shfl_xor(den, 32);
    if (eo == 0){
        float rd = 1.f / (den + 1e-16f);
        float2 bb = *(const float2*)(b2 + c2*2);
        float2 o = make_float2(ax*rd + bb.x, ay*rd + bb.y);
        *(float2*)(out + (size_t)n*16 + c2*2) = o;
    }
}

extern "C" void kernel_launch(void* const* d_in, const int* in_sizes, int n_in,
                              void* d_out, int out_size, void* d_ws, size_t ws_size,
                              hipStream_t stream){
    const float* x     = (const float*)d_in[0];
    const int*   ei    = (const int*)  d_in[1];
    const float* W1    = (const float*)d_in[2];
    const float* asrc1 = (const float*)d_in[3];
    const float* adst1 = (const float*)d_in[4];
    const float* b1    = (const float*)d_in[5];
    const float* W2    = (const float*)d_in[6];
    const float* asrc2 = (const float*)d_in[7];
    const float* adst2 = (const float*)d_in[8];
    const float* b2    = (const float*)d_in[9];
    float* out = (float*)d_out;

    const int N = in_sizes[0] / IN_CH;   // 100000
    const int E = in_sizes[1] / 2;       // 1600000
    const int ETOT = E + N;
    const int NBUCK = (N + NPB - 1) / NPB;   // 391

    char* p = (char*)d_ws;
    auto alloc = [&](size_t bytes) -> char* {
        char* r = p; p += (bytes + 255) & ~(size_t)255; return r;
    };
    __half2* h1h  = (__half2*)alloc((size_t)N * 64 * 4);
    __half2* hl2h = (__half2*)alloc((size_t)N * 64 * 4);
    unsigned char* h1q = (unsigned char*)alloc((size_t)N * 128);
    float2* asw  = (float2*)alloc((size_t)N * 8 * 8);
    float* ad1   = (float*)alloc((size_t)N * 8 * 4);
    __half2* h2h = (__half2*)alloc((size_t)N * 8 * 4);
    float* as2   = (float*)alloc((size_t)N * 4);
    float* ad2   = (float*)alloc((size_t)N * 4);
    int*   bcnt  = (int*)  alloc((size_t)MAXBUCK * 4);
    int*   boffs = (int*)  alloc((size_t)(MAXBUCK + 1) * 4);
    int*   bcur  = (int*)  alloc((size_t)MAXBUCK * 4);
    int*   offs  = (int*)  alloc((size_t)(N + 1) * 4);
    int*   esrc  = (int*)  alloc((size_t)ETOT * 4);
    int*   pbh   = (int*)  alloc((size_t)512 * MAXBUCK * 4);   // per-block bucket hist
    int2*  ebuck = (int2*)hl2h;   // aliases hl2h; k_csr done before k_agg1 writes it

    (void)hipMemsetAsync(bcnt, 0, (size_t)NBUCK * 4, stream);

    const int GPART = 512;
    const int epb = (E + GPART - 1) / GPART;

    k_bhist   <<<GPART, 256, 0, stream>>>(ei + E, E, NBUCK, epb, bcnt, pbh);
    k_bscan   <<<1,     512, 0, stream>>>(bcnt, NBUCK, E, boffs, bcur);
    k_bscatter<<<GPART, 256, 0, stream>>>(ei, E, NBUCK, epb, pbh, bcur, ebuck);
    k_csr     <<<NBUCK, 256, 0, stream>>>(ebuck, boffs, N, E, offs, esrc);

    const int NT = (N + 63) / 64;           // 1563 row tiles
    const int G1 = NT < 512 ? NT : 512;     // 2 blocks/CU, persistent W1
    k_gemm1  <<<G1, 256, 0, stream>>>(x, W1, (__half*)h1h, N, NT);
    k_alpha1 <<<(N * HEADS + 255) / 256, 256, 0, stream>>>(h1h, asrc1, adst1, asw, ad1, h1q, N);

    const int NH = ((N / 2) + 7) & ~7;   // split agg1 for profile visibility
    k_agg1 <<<(NH + 7) / 8, 256, 0, stream>>>(h1q, asw, ad1, offs, esrc, b1, hl2h, 0, NH);
    k_agg1 <<<((N - NH) + 7) / 8, 256, 0, stream>>>(h1q, asw, ad1, offs, esrc, b1, hl2h, NH, N);

    k_gemm2  <<<(N + 63) / 64, 256, 0, stream>>>(hl2h, W2, asrc2, adst2, h2h, as2, ad2, N);
    k_agg2   <<<(N + 3) / 4, 256, 0, stream>>>(h2h, as2, ad2, offs, esrc, b2, out, N);
}

// Round 14
// 305.054 us; speedup vs baseline: 1.0677x; 1.0187x over previous
//
#include <hip/hip_runtime.h>
#include <hip/hip_fp16.h>
#include <math.h>

#define IN_CH 128
#define HEADS 8
#define HID 16
#define OUT_CH 16
#define NEG 0.2f
#define NPB 256          // nodes per bucket (>>8)
#define MAXBUCK 400
#define AST 136          // LDS k-stride in halfs (128 + 8 pad)

__device__ __forceinline__ float lrelu(float x){ return x > 0.f ? x : NEG * x; }
__device__ __forceinline__ float elu_fast(float x){ return x > 0.f ? x : __expf(x) - 1.f; }

typedef _Float16 half8 __attribute__((ext_vector_type(8)));
typedef float    f32x4 __attribute__((ext_vector_type(4)));

// ---------------- bucketed CSR build (bhist spills per-block hist for bscatter reuse) ----------------
__global__ __launch_bounds__(256) void k_bhist(const int* __restrict__ tgt, int E, int nbuck, int epb,
                                               int* __restrict__ bcnt, int* __restrict__ pbh){
    __shared__ int hist[MAXBUCK];
    int tid = threadIdx.x;
    for (int i = tid; i < nbuck; i += 256) hist[i] = 0;
    __syncthreads();
    int start = blockIdx.x * epb, end = min(start + epb, E);
    for (int e = start + tid; e < end; e += 256) atomicAdd(&hist[tgt[e] >> 8], 1);
    __syncthreads();
    int* row = pbh + (size_t)blockIdx.x * MAXBUCK;
    for (int i = tid; i < nbuck; i += 256){
        int h = hist[i];
        row[i] = h;
        if (h) atomicAdd(&bcnt[i], h);
    }
}

__global__ void k_bscan(const int* __restrict__ bcnt, int nbuck, int E,
                        int* __restrict__ boffs, int* __restrict__ bcur){
    __shared__ int s[512];
    int t = threadIdx.x;
    int v = (t < nbuck) ? bcnt[t] : 0;
    int orig = v;
    s[t] = v; __syncthreads();
    for (int off = 1; off < 512; off <<= 1){
        int u = (t >= off) ? s[t - off] : 0;
        __syncthreads();
        v += u; s[t] = v; __syncthreads();
    }
    if (t < nbuck){ boffs[t] = v - orig; bcur[t] = v - orig; }
    if (t == 0) boffs[nbuck] = E;
}

__global__ __launch_bounds__(256) void k_bscatter(const int* __restrict__ ei, int E, int nbuck, int epb,
                                                  const int* __restrict__ pbh,
                                                  int* __restrict__ bcur, int2* __restrict__ ebuck){
    __shared__ int hist[MAXBUCK];
    __shared__ int base[MAXBUCK];
    int tid = threadIdx.x;
    const int* row = pbh + (size_t)blockIdx.x * MAXBUCK;
    for (int i = tid; i < nbuck; i += 256){
        int h = row[i];
        base[i] = h ? atomicAdd(&bcur[i], h) : 0;
        hist[i] = 0;
    }
    __syncthreads();
    int start = blockIdx.x * epb, end = min(start + epb, E);
    for (int e = start + tid; e < end; e += 256){
        int s = ei[e], t = ei[E + e];
        int b = t >> 8;
        int r = atomicAdd(&hist[b], 1);
        ebuck[base[b] + r] = make_int2(s, t);
    }
}

__global__ __launch_bounds__(256) void k_csr(const int2* __restrict__ ebuck, const int* __restrict__ boffs,
                                             int N, int E,
                                             int* __restrict__ offs, int* __restrict__ esrc){
    __shared__ int cnt[256];
    __shared__ int sscan[256];
    __shared__ int wcur[256];
    int b = blockIdx.x;
    int tid = threadIdx.x;
    int n0 = b * 256;
    int nn = min(256, N - n0);
    cnt[tid] = (tid < nn) ? 1 : 0;
    __syncthreads();
    int e0 = boffs[b], e1 = boffs[b + 1];
    for (int e = e0 + tid; e < e1; e += 256) atomicAdd(&cnt[ebuck[e].y & 255], 1);
    __syncthreads();
    int v = cnt[tid], orig = v;
    sscan[tid] = v; __syncthreads();
    for (int off = 1; off < 256; off <<= 1){
        int u = (tid >= off) ? sscan[tid - off] : 0;
        __syncthreads();
        v += u; sscan[tid] = v; __syncthreads();
    }
    int excl = v - orig;
    int gbase = e0 + n0;
    if (tid < nn){
        offs[n0 + tid] = gbase + excl;
        esrc[gbase + excl] = n0 + tid;
    }
    wcur[tid] = excl + 1;
    __syncthreads();
    for (int e = e0 + tid; e < e1; e += 256){
        int2 p = ebuck[e];
        int r = atomicAdd(&wcur[p.y & 255], 1);
        esrc[gbase + r] = p.x;
    }
    if (b == 0 && tid == 0) offs[N] = E + N;
}

// ---------------- GEMM1 (MFMA fp16, persistent W1): h1 = x @ W1 -> fp16 [N][128] ----------------
__global__ __launch_bounds__(256) void k_gemm1(const float* __restrict__ x, const float* __restrict__ W1,
                                               __half* __restrict__ h1, int N, int NT){
    __shared__ _Float16 sB[128*AST];      // 34.8 KB (persistent)
    __shared__ _Float16 sA[2][64*AST];    // 2 x 17.4 KB double buffer
    int tid = threadIdx.x;
    for (int i = tid; i < 128*128; i += 256){
        int k = i >> 7, c = i & 127;
        sB[c*AST + k] = (_Float16)W1[i];
    }
    int wave = tid >> 6, lane = tid & 63;
    int m = lane & 15, quad = lane >> 4;
    int rbase = wave * 16;

    float4 vr[8];
    int tile = blockIdx.x;
    #pragma unroll
    for (int i = 0; i < 8; ++i){
        int q = i*256 + tid;
        int r = q >> 5, seg = q & 31;
        int row = tile*64 + r;
        vr[i] = make_float4(0.f,0.f,0.f,0.f);
        if (tile < NT && row < N) vr[i] = *(const float4*)(x + (size_t)row*128 + seg*4);
    }
    int b = 0;
    for (; tile < NT; tile += gridDim.x){
        #pragma unroll
        for (int i = 0; i < 8; ++i){
            int q = i*256 + tid;
            int r = q >> 5, seg = q & 31;
            _Float16* dst = &sA[b][r*AST + seg*4];
            dst[0]=(_Float16)vr[i].x; dst[1]=(_Float16)vr[i].y;
            dst[2]=(_Float16)vr[i].z; dst[3]=(_Float16)vr[i].w;
        }
        __syncthreads();
        int tn = tile + gridDim.x;
        #pragma unroll
        for (int i = 0; i < 8; ++i){
            int q = i*256 + tid;
            int r = q >> 5, seg = q & 31;
            int row = tn*64 + r;
            vr[i] = make_float4(0.f,0.f,0.f,0.f);
            if (tn < NT && row < N) vr[i] = *(const float4*)(x + (size_t)row*128 + seg*4);
        }
        f32x4 acc[8] = {};
        #pragma unroll
        for (int kc = 0; kc < 4; ++kc){
            int kb = kc*32 + quad*8;
            half8 a = *(half8*)(&sA[b][(rbase + m)*AST + kb]);
            #pragma unroll
            for (int t = 0; t < 8; ++t){
                half8 bb = *(half8*)(&sB[(t*16 + m)*AST + kb]);
                acc[t] = __builtin_amdgcn_mfma_f32_16x16x32_f16(a, bb, acc[t], 0, 0, 0);
            }
        }
        int row0 = tile*64;
        #pragma unroll
        for (int t = 0; t < 8; ++t){
            #pragma unroll
            for (int j = 0; j < 4; ++j){
                int r = row0 + rbase + quad*4 + j;
                if (r < N) h1[(size_t)r*128 + t*16 + m] = __float2half(acc[t][j]);
            }
        }
        b ^= 1;
    }
}

// ---------------- attention logits + per-(node,head) int8 quantization ----------------
struct H8 { __half2 v[8]; };

__global__ void k_alpha1(const __half2* __restrict__ h1h, const float* __restrict__ asrc, const float* __restrict__ adst,
                         float2* __restrict__ asw, float* __restrict__ ad1,
                         unsigned char* __restrict__ h1q, int N){
    int idx = blockIdx.x*blockDim.x + threadIdx.x;
    if (idx >= N*HEADS) return;
    int h = idx & 7;
    int n = idx >> 3;
    H8 blk = *(const H8*)(h1h + (size_t)n*64 + h*8);
    const float2* sp = (const float2*)(asrc + h*16);
    const float2* dp = (const float2*)(adst + h*16);
    float fv[16];
    float ss = 0.f, dd = 0.f;
    #pragma unroll
    for (int j = 0; j < 8; ++j){
        float2 v = __half22float2(blk.v[j]);
        fv[2*j] = v.x; fv[2*j+1] = v.y;
        float2 a = sp[j], b = dp[j];
        ss += v.x*a.x + v.y*a.y;
        dd += v.x*b.x + v.y*b.y;
    }
    float mx = 1e-12f;
    #pragma unroll
    for (int k = 0; k < 16; ++k) mx = fmaxf(mx, fabsf(fv[k]));
    float rs = 127.f / mx;
    unsigned int w[4];
    #pragma unroll
    for (int d = 0; d < 4; ++d){
        unsigned int b0 = (unsigned int)((int)rintf(fv[4*d+0]*rs) + 128);
        unsigned int b1 = (unsigned int)((int)rintf(fv[4*d+1]*rs) + 128);
        unsigned int b2 = (unsigned int)((int)rintf(fv[4*d+2]*rs) + 128);
        unsigned int b3 = (unsigned int)((int)rintf(fv[4*d+3]*rs) + 128);
        w[d] = b0 | (b1 << 8) | (b2 << 16) | (b3 << 24);
    }
    asw[idx] = make_float2(ss, mx * (1.f/127.f));
    ad1[idx] = dd;
    *(uint4*)(h1q + (size_t)idx*16) = make_uint4(w[0], w[1], w[2], w[3]);
}

// ---------------- layer-1 aggregation: int8 gather, depth-2 software pipeline ----------------
// 2 nodes/wave, 4 edge-slots x 8 head-lanes, 16 ch/lane. Pipeline: esrc for it+2 and
// dependent (asw,h1q) for it+1 issue before it's compute -> the esrc->asw/h1q chain no
// longer serializes per iteration. Tail slots: w=0 + clamped index (exact no-op).
__global__ __launch_bounds__(256) void k_agg1(const unsigned char* __restrict__ h1q, const float2* __restrict__ asw,
                                              const float* __restrict__ ad1,
                                              const int* __restrict__ offs, const int* __restrict__ esrc,
                                              const float* __restrict__ b1, __half2* __restrict__ hl2h, int N){
    int wv = threadIdx.x >> 6;
    int l  = threadIdx.x & 63;
    int nsub = l >> 5;
    int slot = (l >> 3) & 3;
    int c    = l & 7;
    int n = blockIdx.x*8 + wv*2 + nsub;
    bool alive = (n < N);
    float adc = 0.f;
    int e0 = 0, deg = 0;
    if (alive){
        adc = ad1[n*8 + c];
        e0 = offs[n];
        deg = offs[n+1] - e0;
    }
    int degmax = max(deg, __shfl_xor(deg, 32));
    int nit = (degmax + 7) >> 3;

    // pipeline prologue: stage A (esrc) for it=0,1; stage B (asw,h1q) for it=0
    int j0 = slot, j1 = 4 + slot;
    bool v0a = j0 < deg, v1a = j1 < deg;
    int s0 = esrc[e0 + (v0a ? j0 : 0)];
    int s1 = esrc[e0 + (v1a ? j1 : 0)];
    int j0b = 8 + slot, j1b = 12 + slot;
    bool v0b = j0b < deg, v1b = j1b < deg;
    int s0b = esrc[e0 + (v0b ? j0b : 0)];
    int s1b = esrc[e0 + (v1b ? j1b : 0)];
    float2 aw0 = asw[s0*8 + c];
    float2 aw1 = asw[s1*8 + c];
    uint4 q0 = *(const uint4*)(h1q + (size_t)s0*128 + c*16);
    uint4 q1 = *(const uint4*)(h1q + (size_t)s1*128 + c*16);

    float acc[16] = {};
    float den = 0.f;     // sum of w
    float dq  = 0.f;     // sum of w*scale
    for (int it = 0; it < nit; ++it){
        int ja = (it+2)*8 + slot, jb = ja + 4;
        bool nv0 = ja < deg, nv1 = jb < deg;
        int ns0 = esrc[e0 + (nv0 ? ja : 0)];
        int ns1 = esrc[e0 + (nv1 ? jb : 0)];
        float2 naw0 = asw[s0b*8 + c];
        float2 naw1 = asw[s1b*8 + c];
        uint4 nq0 = *(const uint4*)(h1q + (size_t)s0b*128 + c*16);
        uint4 nq1 = *(const uint4*)(h1q + (size_t)s1b*128 + c*16);

        float w0 = v0a ? __expf(lrelu(aw0.x + adc)) : 0.f;
        float w1 = v1a ? __expf(lrelu(aw1.x + adc)) : 0.f;
        float wq0 = w0 * aw0.y;
        float wq1 = w1 * aw1.y;
        den += w0 + w1;
        dq  += wq0 + wq1;
        const unsigned int* u0 = (const unsigned int*)&q0;
        const unsigned int* u1 = (const unsigned int*)&q1;
        #pragma unroll
        for (int d = 0; d < 4; ++d){
            unsigned int a = u0[d], b = u1[d];
            acc[4*d+0] += wq0 * (float)(a & 255u);
            acc[4*d+1] += wq0 * (float)((a >> 8) & 255u);
            acc[4*d+2] += wq0 * (float)((a >> 16) & 255u);
            acc[4*d+3] += wq0 * (float)(a >> 24);
            acc[4*d+0] += wq1 * (float)(b & 255u);
            acc[4*d+1] += wq1 * (float)((b >> 8) & 255u);
            acc[4*d+2] += wq1 * (float)((b >> 16) & 255u);
            acc[4*d+3] += wq1 * (float)(b >> 24);
        }
        v0a = v0b; v1a = v1b;
        aw0 = naw0; aw1 = naw1; q0 = nq0; q1 = nq1;
        v0b = nv0; v1b = nv1; s0b = ns0; s1b = ns1;
    }
    den += __shfl_xor(den, 8);  den += __shfl_xor(den, 16);
    dq  += __shfl_xor(dq, 8);   dq  += __shfl_xor(dq, 16);
    #pragma unroll
    for (int k = 0; k < 16; ++k){
        acc[k] += __shfl_xor(acc[k], 8);
        acc[k] += __shfl_xor(acc[k], 16);
    }
    if (!alive) return;
    float rd = 1.f / (den + 1e-16f);
    float bias128 = 128.f * dq;
    float sel0, sel1, sel2, sel3;
    {
        float a0 = (slot & 1) ? acc[4]  : acc[0];
        float b0 = (slot & 1) ? acc[12] : acc[8];
        sel0 = (slot & 2) ? b0 : a0;
        float a1 = (slot & 1) ? acc[5]  : acc[1];
        float b1v = (slot & 1) ? acc[13] : acc[9];
        sel1 = (slot & 2) ? b1v : a1;
        float a2 = (slot & 1) ? acc[6]  : acc[2];
        float b2v = (slot & 1) ? acc[14] : acc[10];
        sel2 = (slot & 2) ? b2v : a2;
        float a3 = (slot & 1) ? acc[7]  : acc[3];
        float b3v = (slot & 1) ? acc[15] : acc[11];
        sel3 = (slot & 2) ? b3v : a3;
    }
    float4 b4 = *(const float4*)(b1 + c*16 + slot*4);
    float v0 = elu_fast((sel0 - bias128)*rd + b4.x);
    float v1 = elu_fast((sel1 - bias128)*rd + b4.y);
    float v2 = elu_fast((sel2 - bias128)*rd + b4.z);
    float v3 = elu_fast((sel3 - bias128)*rd + b4.w);
    __half2 q0h = __floats2half2_rn(v0, v1);
    __half2 q1h = __floats2half2_rn(v2, v3);
    float2 ov;
    *(__half2*)&ov.x = q0h; *(__half2*)&ov.y = q1h;
    *(float2*)(hl2h + (size_t)n*64 + c*8 + slot*2) = ov;
}

// ---------------- GEMM2: h2 = hl2 @ W2 -> fp16 + fused alpha2 ----------------
#define FMA4(acc, a, b) { acc.x += (a)*(b).x; acc.y += (a)*(b).y; acc.z += (a)*(b).z; acc.w += (a)*(b).w; }

__global__ __launch_bounds__(256) void k_gemm2(const __half2* __restrict__ hl2h, const float* __restrict__ W2,
                                               const float* __restrict__ asrc2, const float* __restrict__ adst2,
                                               __half2* __restrict__ h2h, float* __restrict__ as2, float* __restrict__ ad2,
                                               int N){
    __shared__ float sX[64*132];
    __shared__ float sW2[128*16];
    int tid = threadIdx.x;
    for (int i = tid; i < 128*16; i += 256) sW2[i] = W2[i];
    int row0 = blockIdx.x * 64;
    #pragma unroll
    for (int i = 0; i < 4; ++i){
        int q = i*256 + tid;
        int r = q >> 4, seg = q & 15;
        float4 raw = make_float4(0.f,0.f,0.f,0.f);
        if (row0 + r < N) raw = ((const float4*)(hl2h + (size_t)(row0+r)*64))[seg];
        const __half2* hp = (const __half2*)&raw;
        float* dst = &sX[r*132 + seg*8];
        #pragma unroll
        for (int j = 0; j < 4; ++j){
            float2 f = __half22float2(hp[j]);
            dst[2*j] = f.x; dst[2*j+1] = f.y;
        }
    }
    __syncthreads();
    int nd = tid >> 2;
    int cq = tid & 3, c0 = cq*4;
    int n = row0 + nd;
    float4 acc = make_float4(0.f,0.f,0.f,0.f);
    #pragma unroll 4
    for (int k4 = 0; k4 < 32; ++k4){
        float4 a  = *(const float4*)(&sX[nd*132 + k4*4]);
        float4 w0 = *(const float4*)(&sW2[(k4*4+0)*16 + c0]);
        float4 w1 = *(const float4*)(&sW2[(k4*4+1)*16 + c0]);
        float4 w2 = *(const float4*)(&sW2[(k4*4+2)*16 + c0]);
        float4 w3 = *(const float4*)(&sW2[(k4*4+3)*16 + c0]);
        FMA4(acc, a.x, w0); FMA4(acc, a.y, w1); FMA4(acc, a.z, w2); FMA4(acc, a.w, w3);
    }
    float ps = acc.x*asrc2[c0] + acc.y*asrc2[c0+1] + acc.z*asrc2[c0+2] + acc.w*asrc2[c0+3];
    float pd = acc.x*adst2[c0] + acc.y*adst2[c0+1] + acc.z*adst2[c0+2] + acc.w*adst2[c0+3];
    ps += __shfl_xor(ps, 1); ps += __shfl_xor(ps, 2);
    pd += __shfl_xor(pd, 1); pd += __shfl_xor(pd, 2);
    if (n < N){
        __half2 p0 = __floats2half2_rn(acc.x, acc.y);
        __half2 p1 = __floats2half2_rn(acc.z, acc.w);
        float2 ov;
        *(__half2*)&ov.x = p0; *(__half2*)&ov.y = p1;
        *(float2*)(h2h + (size_t)n*8 + cq*2) = ov;
        if (cq == 0){ as2[n] = ps; ad2[n] = pd; }
    }
}

// ---------------- layer-2 aggregation: depth-2 software pipeline ----------------
// 1 node/wave, 8 edge-slots x 8 lanes, 2 ch/lane (half2). deg is wave-uniform.
// esrc for it+2 and dependent (as2,h2) for it+1 issue before it's compute.
__global__ __launch_bounds__(256) void k_agg2(const __half2* __restrict__ h2h, const float* __restrict__ as2v,
                                              const float* __restrict__ ad2v,
                                              const int* __restrict__ offs, const int* __restrict__ esrc,
                                              const float* __restrict__ b2, float* __restrict__ out, int N){
    int n = blockIdx.x*4 + (threadIdx.x >> 6);
    if (n >= N) return;
    int l = threadIdx.x & 63;
    int eo = l >> 3, c2 = l & 7;
    int e0 = offs[n];
    int deg = offs[n+1] - e0;
    float ad = ad2v[n];
    int nit = (deg + 7) >> 3;

    bool va = eo < deg;
    int sa = esrc[e0 + (va ? eo : 0)];
    bool vb = (8 + eo) < deg;
    int sb = esrc[e0 + (vb ? 8 + eo : 0)];
    float asa = as2v[sa];
    float2 fa = __half22float2(h2h[(size_t)sa*8 + c2]);

    float ax = 0.f, ay = 0.f, den = 0.f;
    for (int it = 0; it < nit; ++it){
        int jn = (it+2)*8 + eo;
        bool vn = jn < deg;
        int sn = esrc[e0 + (vn ? jn : 0)];
        float nas = as2v[sb];
        float2 nf = __half22float2(h2h[(size_t)sb*8 + c2]);

        float w = va ? __expf(lrelu(asa + ad)) : 0.f;
        den += w;
        ax += w * fa.x; ay += w * fa.y;

        va = vb; asa = nas; fa = nf;
        vb = vn; sb = sn;
    }
    ax += __shfl_xor(ax, 8);  ay += __shfl_xor(ay, 8);  den += __shfl_xor(den, 8);
    ax += __shfl_xor(ax, 16); ay += __shfl_xor(ay, 16); den += __shfl_xor(den, 16);
    ax += __shfl_xor(ax, 32); ay += __shfl_xor(ay, 32); den += __shfl_xor(den, 32);
    if (eo == 0){
        float rd = 1.f / (den + 1e-16f);
        float2 bb = *(const float2*)(b2 + c2*2);
        float2 o = make_float2(ax*rd + bb.x, ay*rd + bb.y);
        *(float2*)(out + (size_t)n*16 + c2*2) = o;
    }
}

extern "C" void kernel_launch(void* const* d_in, const int* in_sizes, int n_in,
                              void* d_out, int out_size, void* d_ws, size_t ws_size,
                              hipStream_t stream){
    const float* x     = (const float*)d_in[0];
    const int*   ei    = (const int*)  d_in[1];
    const float* W1    = (const float*)d_in[2];
    const float* asrc1 = (const float*)d_in[3];
    const float* adst1 = (const float*)d_in[4];
    const float* b1    = (const float*)d_in[5];
    const float* W2    = (const float*)d_in[6];
    const float* asrc2 = (const float*)d_in[7];
    const float* adst2 = (const float*)d_in[8];
    const float* b2    = (const float*)d_in[9];
    float* out = (float*)d_out;

    const int N = in_sizes[0] / IN_CH;   // 100000
    const int E = in_sizes[1] / 2;       // 1600000
    const int ETOT = E + N;
    const int NBUCK = (N + NPB - 1) / NPB;   // 391

    char* p = (char*)d_ws;
    auto alloc = [&](size_t bytes) -> char* {
        char* r = p; p += (bytes + 255) & ~(size_t)255; return r;
    };
    __half2* h1h  = (__half2*)alloc((size_t)N * 64 * 4);
    __half2* hl2h = (__half2*)alloc((size_t)N * 64 * 4);
    unsigned char* h1q = (unsigned char*)alloc((size_t)N * 128);
    float2* asw  = (float2*)alloc((size_t)N * 8 * 8);
    float* ad1   = (float*)alloc((size_t)N * 8 * 4);
    __half2* h2h = (__half2*)alloc((size_t)N * 8 * 4);
    float* as2   = (float*)alloc((size_t)N * 4);
    float* ad2   = (float*)alloc((size_t)N * 4);
    int*   bcnt  = (int*)  alloc((size_t)MAXBUCK * 4);
    int*   boffs = (int*)  alloc((size_t)(MAXBUCK + 1) * 4);
    int*   bcur  = (int*)  alloc((size_t)MAXBUCK * 4);
    int*   offs  = (int*)  alloc((size_t)(N + 1) * 4);
    int*   esrc  = (int*)  alloc((size_t)ETOT * 4);
    int*   pbh   = (int*)  alloc((size_t)512 * MAXBUCK * 4);   // per-block bucket hist
    int2*  ebuck = (int2*)hl2h;   // aliases hl2h; k_csr done before k_agg1 writes it

    (void)hipMemsetAsync(bcnt, 0, (size_t)NBUCK * 4, stream);

    const int GPART = 512;
    const int epb = (E + GPART - 1) / GPART;

    k_bhist   <<<GPART, 256, 0, stream>>>(ei + E, E, NBUCK, epb, bcnt, pbh);
    k_bscan   <<<1,     512, 0, stream>>>(bcnt, NBUCK, E, boffs, bcur);
    k_bscatter<<<GPART, 256, 0, stream>>>(ei, E, NBUCK, epb, pbh, bcur, ebuck);
    k_csr     <<<NBUCK, 256, 0, stream>>>(ebuck, boffs, N, E, offs, esrc);

    const int NT = (N + 63) / 64;           // 1563 row tiles
    const int G1 = NT < 512 ? NT : 512;     // 2 blocks/CU, persistent W1
    k_gemm1  <<<G1, 256, 0, stream>>>(x, W1, (__half*)h1h, N, NT);
    k_alpha1 <<<(N * HEADS + 255) / 256, 256, 0, stream>>>(h1h, asrc1, adst1, asw, ad1, h1q, N);

    k_agg1   <<<(N + 7) / 8, 256, 0, stream>>>(h1q, asw, ad1, offs, esrc, b1, hl2h, N);

    k_gemm2  <<<(N + 63) / 64, 256, 0, stream>>>(hl2h, W2, asrc2, adst2, h2h, as2, ad2, N);
    k_agg2   <<<(N + 3) / 4, 256, 0, stream>>>(h2h, as2, ad2, offs, esrc, b2, out, N);
}

// Round 15
// 295.456 us; speedup vs baseline: 1.1024x; 1.0325x over previous
//
#include <hip/hip_runtime.h>
#include <hip/hip_fp16.h>
#include <math.h>

#define IN_CH 128
#define HEADS 8
#define HID 16
#define OUT_CH 16
#define NEG 0.2f
#define NPB 256          // nodes per bucket (>>8)
#define MAXBUCK 400
#define AST 136          // LDS k-stride in halfs (128 + 8 pad)

__device__ __forceinline__ float lrelu(float x){ return x > 0.f ? x : NEG * x; }
__device__ __forceinline__ float elu_fast(float x){ return x > 0.f ? x : __expf(x) - 1.f; }

typedef _Float16 half8 __attribute__((ext_vector_type(8)));
typedef float    f32x4 __attribute__((ext_vector_type(4)));

// ---------------- bucketed CSR build (bhist spills per-block hist for bscatter reuse) ----------------
__global__ __launch_bounds__(256) void k_bhist(const int* __restrict__ tgt, int E, int nbuck, int epb,
                                               int* __restrict__ bcnt, int* __restrict__ pbh){
    __shared__ int hist[MAXBUCK];
    int tid = threadIdx.x;
    for (int i = tid; i < nbuck; i += 256) hist[i] = 0;
    __syncthreads();
    int start = blockIdx.x * epb, end = min(start + epb, E);
    for (int e = start + tid; e < end; e += 256) atomicAdd(&hist[tgt[e] >> 8], 1);
    __syncthreads();
    int* row = pbh + (size_t)blockIdx.x * MAXBUCK;
    for (int i = tid; i < nbuck; i += 256){
        int h = hist[i];
        row[i] = h;
        if (h) atomicAdd(&bcnt[i], h);
    }
}

__global__ void k_bscan(const int* __restrict__ bcnt, int nbuck, int E,
                        int* __restrict__ boffs, int* __restrict__ bcur){
    __shared__ int s[512];
    int t = threadIdx.x;
    int v = (t < nbuck) ? bcnt[t] : 0;
    int orig = v;
    s[t] = v; __syncthreads();
    for (int off = 1; off < 512; off <<= 1){
        int u = (t >= off) ? s[t - off] : 0;
        __syncthreads();
        v += u; s[t] = v; __syncthreads();
    }
    if (t < nbuck){ boffs[t] = v - orig; bcur[t] = v - orig; }
    if (t == 0) boffs[nbuck] = E;
}

__global__ __launch_bounds__(256) void k_bscatter(const int* __restrict__ ei, int E, int nbuck, int epb,
                                                  const int* __restrict__ pbh,
                                                  int* __restrict__ bcur, int2* __restrict__ ebuck){
    __shared__ int hist[MAXBUCK];
    __shared__ int base[MAXBUCK];
    int tid = threadIdx.x;
    const int* row = pbh + (size_t)blockIdx.x * MAXBUCK;
    for (int i = tid; i < nbuck; i += 256){
        int h = row[i];
        base[i] = h ? atomicAdd(&bcur[i], h) : 0;
        hist[i] = 0;
    }
    __syncthreads();
    int start = blockIdx.x * epb, end = min(start + epb, E);
    for (int e = start + tid; e < end; e += 256){
        int s = ei[e], t = ei[E + e];
        int b = t >> 8;
        int r = atomicAdd(&hist[b], 1);
        ebuck[base[b] + r] = make_int2(s, t);
    }
}

__global__ __launch_bounds__(256) void k_csr(const int2* __restrict__ ebuck, const int* __restrict__ boffs,
                                             int N, int E,
                                             int* __restrict__ offs, int* __restrict__ esrc){
    __shared__ int cnt[256];
    __shared__ int sscan[256];
    __shared__ int wcur[256];
    int b = blockIdx.x;
    int tid = threadIdx.x;
    int n0 = b * 256;
    int nn = min(256, N - n0);
    cnt[tid] = (tid < nn) ? 1 : 0;
    __syncthreads();
    int e0 = boffs[b], e1 = boffs[b + 1];
    for (int e = e0 + tid; e < e1; e += 256) atomicAdd(&cnt[ebuck[e].y & 255], 1);
    __syncthreads();
    int v = cnt[tid], orig = v;
    sscan[tid] = v; __syncthreads();
    for (int off = 1; off < 256; off <<= 1){
        int u = (tid >= off) ? sscan[tid - off] : 0;
        __syncthreads();
        v += u; sscan[tid] = v; __syncthreads();
    }
    int excl = v - orig;
    int gbase = e0 + n0;
    if (tid < nn){
        offs[n0 + tid] = gbase + excl;
        esrc[gbase + excl] = n0 + tid;
    }
    wcur[tid] = excl + 1;
    __syncthreads();
    for (int e = e0 + tid; e < e1; e += 256){
        int2 p = ebuck[e];
        int r = atomicAdd(&wcur[p.y & 255], 1);
        esrc[gbase + r] = p.x;
    }
    if (b == 0 && tid == 0) offs[N] = E + N;
}

// ---------------- GEMM1 (MFMA fp16, persistent W1): h1 = x @ W1 -> fp16 [N][128] ----------------
__global__ __launch_bounds__(256) void k_gemm1(const float* __restrict__ x, const float* __restrict__ W1,
                                               __half* __restrict__ h1, int N, int NT){
    __shared__ _Float16 sB[128*AST];      // 34.8 KB (persistent)
    __shared__ _Float16 sA[2][64*AST];    // 2 x 17.4 KB double buffer
    int tid = threadIdx.x;
    for (int i = tid; i < 128*128; i += 256){
        int k = i >> 7, c = i & 127;
        sB[c*AST + k] = (_Float16)W1[i];
    }
    int wave = tid >> 6, lane = tid & 63;
    int m = lane & 15, quad = lane >> 4;
    int rbase = wave * 16;

    float4 vr[8];
    int tile = blockIdx.x;
    #pragma unroll
    for (int i = 0; i < 8; ++i){
        int q = i*256 + tid;
        int r = q >> 5, seg = q & 31;
        int row = tile*64 + r;
        vr[i] = make_float4(0.f,0.f,0.f,0.f);
        if (tile < NT && row < N) vr[i] = *(const float4*)(x + (size_t)row*128 + seg*4);
    }
    int b = 0;
    for (; tile < NT; tile += gridDim.x){
        #pragma unroll
        for (int i = 0; i < 8; ++i){
            int q = i*256 + tid;
            int r = q >> 5, seg = q & 31;
            _Float16* dst = &sA[b][r*AST + seg*4];
            dst[0]=(_Float16)vr[i].x; dst[1]=(_Float16)vr[i].y;
            dst[2]=(_Float16)vr[i].z; dst[3]=(_Float16)vr[i].w;
        }
        __syncthreads();
        int tn = tile + gridDim.x;
        #pragma unroll
        for (int i = 0; i < 8; ++i){
            int q = i*256 + tid;
            int r = q >> 5, seg = q & 31;
            int row = tn*64 + r;
            vr[i] = make_float4(0.f,0.f,0.f,0.f);
            if (tn < NT && row < N) vr[i] = *(const float4*)(x + (size_t)row*128 + seg*4);
        }
        f32x4 acc[8] = {};
        #pragma unroll
        for (int kc = 0; kc < 4; ++kc){
            int kb = kc*32 + quad*8;
            half8 a = *(half8*)(&sA[b][(rbase + m)*AST + kb]);
            #pragma unroll
            for (int t = 0; t < 8; ++t){
                half8 bb = *(half8*)(&sB[(t*16 + m)*AST + kb]);
                acc[t] = __builtin_amdgcn_mfma_f32_16x16x32_f16(a, bb, acc[t], 0, 0, 0);
            }
        }
        int row0 = tile*64;
        #pragma unroll
        for (int t = 0; t < 8; ++t){
            #pragma unroll
            for (int j = 0; j < 4; ++j){
                int r = row0 + rbase + quad*4 + j;
                if (r < N) h1[(size_t)r*128 + t*16 + m] = __float2half(acc[t][j]);
            }
        }
        b ^= 1;
    }
}

// ---------------- attention logits + per-(node,head) int8 quantization ----------------
struct H8 { __half2 v[8]; };

__global__ void k_alpha1(const __half2* __restrict__ h1h, const float* __restrict__ asrc, const float* __restrict__ adst,
                         float2* __restrict__ asw, float* __restrict__ ad1,
                         unsigned char* __restrict__ h1q, int N){
    int idx = blockIdx.x*blockDim.x + threadIdx.x;
    if (idx >= N*HEADS) return;
    int h = idx & 7;
    int n = idx >> 3;
    H8 blk = *(const H8*)(h1h + (size_t)n*64 + h*8);
    const float2* sp = (const float2*)(asrc + h*16);
    const float2* dp = (const float2*)(adst + h*16);
    float fv[16];
    float ss = 0.f, dd = 0.f;
    #pragma unroll
    for (int j = 0; j < 8; ++j){
        float2 v = __half22float2(blk.v[j]);
        fv[2*j] = v.x; fv[2*j+1] = v.y;
        float2 a = sp[j], b = dp[j];
        ss += v.x*a.x + v.y*a.y;
        dd += v.x*b.x + v.y*b.y;
    }
    float mx = 1e-12f;
    #pragma unroll
    for (int k = 0; k < 16; ++k) mx = fmaxf(mx, fabsf(fv[k]));
    float rs = 127.f / mx;
    unsigned int w[4];
    #pragma unroll
    for (int d = 0; d < 4; ++d){
        unsigned int b0 = (unsigned int)((int)rintf(fv[4*d+0]*rs) + 128);
        unsigned int b1 = (unsigned int)((int)rintf(fv[4*d+1]*rs) + 128);
        unsigned int b2 = (unsigned int)((int)rintf(fv[4*d+2]*rs) + 128);
        unsigned int b3 = (unsigned int)((int)rintf(fv[4*d+3]*rs) + 128);
        w[d] = b0 | (b1 << 8) | (b2 << 16) | (b3 << 24);
    }
    asw[idx] = make_float2(ss, mx * (1.f/127.f));
    ad1[idx] = dd;
    *(uint4*)(h1q + (size_t)idx*16) = make_uint4(w[0], w[1], w[2], w[3]);
}

// ---------------- layer-1 aggregation: int8 gather, depth-2 software pipeline ----------------
// 2 nodes/wave, 4 edge-slots x 8 head-lanes, 16 ch/lane. Pipeline: esrc for it+2 and
// dependent (asw,h1q) for it+1 issue before it's compute. Tail slots: w=0 + clamped idx.
__global__ __launch_bounds__(256) void k_agg1(const unsigned char* __restrict__ h1q, const float2* __restrict__ asw,
                                              const float* __restrict__ ad1,
                                              const int* __restrict__ offs, const int* __restrict__ esrc,
                                              const float* __restrict__ b1, __half2* __restrict__ hl2h, int N){
    int wv = threadIdx.x >> 6;
    int l  = threadIdx.x & 63;
    int nsub = l >> 5;
    int slot = (l >> 3) & 3;
    int c    = l & 7;
    int n = blockIdx.x*8 + wv*2 + nsub;
    bool alive = (n < N);
    float adc = 0.f;
    int e0 = 0, deg = 0;
    if (alive){
        adc = ad1[n*8 + c];
        e0 = offs[n];
        deg = offs[n+1] - e0;
    }
    int degmax = max(deg, __shfl_xor(deg, 32));
    int nit = (degmax + 7) >> 3;

    // pipeline prologue: stage A (esrc) for it=0,1; stage B (asw,h1q) for it=0
    int j0 = slot, j1 = 4 + slot;
    bool v0a = j0 < deg, v1a = j1 < deg;
    int s0 = esrc[e0 + (v0a ? j0 : 0)];
    int s1 = esrc[e0 + (v1a ? j1 : 0)];
    int j0b = 8 + slot, j1b = 12 + slot;
    bool v0b = j0b < deg, v1b = j1b < deg;
    int s0b = esrc[e0 + (v0b ? j0b : 0)];
    int s1b = esrc[e0 + (v1b ? j1b : 0)];
    float2 aw0 = asw[s0*8 + c];
    float2 aw1 = asw[s1*8 + c];
    uint4 q0 = *(const uint4*)(h1q + (size_t)s0*128 + c*16);
    uint4 q1 = *(const uint4*)(h1q + (size_t)s1*128 + c*16);

    float acc[16] = {};
    float den = 0.f;     // sum of w
    float dq  = 0.f;     // sum of w*scale
    for (int it = 0; it < nit; ++it){
        int ja = (it+2)*8 + slot, jb = ja + 4;
        bool nv0 = ja < deg, nv1 = jb < deg;
        int ns0 = esrc[e0 + (nv0 ? ja : 0)];
        int ns1 = esrc[e0 + (nv1 ? jb : 0)];
        float2 naw0 = asw[s0b*8 + c];
        float2 naw1 = asw[s1b*8 + c];
        uint4 nq0 = *(const uint4*)(h1q + (size_t)s0b*128 + c*16);
        uint4 nq1 = *(const uint4*)(h1q + (size_t)s1b*128 + c*16);

        float w0 = v0a ? __expf(lrelu(aw0.x + adc)) : 0.f;
        float w1 = v1a ? __expf(lrelu(aw1.x + adc)) : 0.f;
        float wq0 = w0 * aw0.y;
        float wq1 = w1 * aw1.y;
        den += w0 + w1;
        dq  += wq0 + wq1;
        const unsigned int* u0 = (const unsigned int*)&q0;
        const unsigned int* u1 = (const unsigned int*)&q1;
        #pragma unroll
        for (int d = 0; d < 4; ++d){
            unsigned int a = u0[d], b = u1[d];
            acc[4*d+0] += wq0 * (float)(a & 255u);
            acc[4*d+1] += wq0 * (float)((a >> 8) & 255u);
            acc[4*d+2] += wq0 * (float)((a >> 16) & 255u);
            acc[4*d+3] += wq0 * (float)(a >> 24);
            acc[4*d+0] += wq1 * (float)(b & 255u);
            acc[4*d+1] += wq1 * (float)((b >> 8) & 255u);
            acc[4*d+2] += wq1 * (float)((b >> 16) & 255u);
            acc[4*d+3] += wq1 * (float)(b >> 24);
        }
        v0a = v0b; v1a = v1b;
        aw0 = naw0; aw1 = naw1; q0 = nq0; q1 = nq1;
        v0b = nv0; v1b = nv1; s0b = ns0; s1b = ns1;
    }
    den += __shfl_xor(den, 8);  den += __shfl_xor(den, 16);
    dq  += __shfl_xor(dq, 8);   dq  += __shfl_xor(dq, 16);
    #pragma unroll
    for (int k = 0; k < 16; ++k){
        acc[k] += __shfl_xor(acc[k], 8);
        acc[k] += __shfl_xor(acc[k], 16);
    }
    if (!alive) return;
    float rd = 1.f / (den + 1e-16f);
    float bias128 = 128.f * dq;
    float sel0, sel1, sel2, sel3;
    {
        float a0 = (slot & 1) ? acc[4]  : acc[0];
        float b0 = (slot & 1) ? acc[12] : acc[8];
        sel0 = (slot & 2) ? b0 : a0;
        float a1 = (slot & 1) ? acc[5]  : acc[1];
        float b1v = (slot & 1) ? acc[13] : acc[9];
        sel1 = (slot & 2) ? b1v : a1;
        float a2 = (slot & 1) ? acc[6]  : acc[2];
        float b2v = (slot & 1) ? acc[14] : acc[10];
        sel2 = (slot & 2) ? b2v : a2;
        float a3 = (slot & 1) ? acc[7]  : acc[3];
        float b3v = (slot & 1) ? acc[15] : acc[11];
        sel3 = (slot & 2) ? b3v : a3;
    }
    float4 b4 = *(const float4*)(b1 + c*16 + slot*4);
    float v0 = elu_fast((sel0 - bias128)*rd + b4.x);
    float v1 = elu_fast((sel1 - bias128)*rd + b4.y);
    float v2 = elu_fast((sel2 - bias128)*rd + b4.z);
    float v3 = elu_fast((sel3 - bias128)*rd + b4.w);
    __half2 q0h = __floats2half2_rn(v0, v1);
    __half2 q1h = __floats2half2_rn(v2, v3);
    float2 ov;
    *(__half2*)&ov.x = q0h; *(__half2*)&ov.y = q1h;
    *(float2*)(hl2h + (size_t)n*64 + c*8 + slot*2) = ov;
}

// ---------------- GEMM2: h2 = hl2 @ W2 -> fp16 + fused alpha2 ----------------
#define FMA4(acc, a, b) { acc.x += (a)*(b).x; acc.y += (a)*(b).y; acc.z += (a)*(b).z; acc.w += (a)*(b).w; }

__global__ __launch_bounds__(256) void k_gemm2(const __half2* __restrict__ hl2h, const float* __restrict__ W2,
                                               const float* __restrict__ asrc2, const float* __restrict__ adst2,
                                               __half2* __restrict__ h2h, float* __restrict__ as2, float* __restrict__ ad2,
                                               int N){
    __shared__ float sX[64*132];
    __shared__ float sW2[128*16];
    int tid = threadIdx.x;
    for (int i = tid; i < 128*16; i += 256) sW2[i] = W2[i];
    int row0 = blockIdx.x * 64;
    #pragma unroll
    for (int i = 0; i < 4; ++i){
        int q = i*256 + tid;
        int r = q >> 4, seg = q & 15;
        float4 raw = make_float4(0.f,0.f,0.f,0.f);
        if (row0 + r < N) raw = ((const float4*)(hl2h + (size_t)(row0+r)*64))[seg];
        const __half2* hp = (const __half2*)&raw;
        float* dst = &sX[r*132 + seg*8];
        #pragma unroll
        for (int j = 0; j < 4; ++j){
            float2 f = __half22float2(hp[j]);
            dst[2*j] = f.x; dst[2*j+1] = f.y;
        }
    }
    __syncthreads();
    int nd = tid >> 2;
    int cq = tid & 3, c0 = cq*4;
    int n = row0 + nd;
    float4 acc = make_float4(0.f,0.f,0.f,0.f);
    #pragma unroll 4
    for (int k4 = 0; k4 < 32; ++k4){
        float4 a  = *(const float4*)(&sX[nd*132 + k4*4]);
        float4 w0 = *(const float4*)(&sW2[(k4*4+0)*16 + c0]);
        float4 w1 = *(const float4*)(&sW2[(k4*4+1)*16 + c0]);
        float4 w2 = *(const float4*)(&sW2[(k4*4+2)*16 + c0]);
        float4 w3 = *(const float4*)(&sW2[(k4*4+3)*16 + c0]);
        FMA4(acc, a.x, w0); FMA4(acc, a.y, w1); FMA4(acc, a.z, w2); FMA4(acc, a.w, w3);
    }
    float ps = acc.x*asrc2[c0] + acc.y*asrc2[c0+1] + acc.z*asrc2[c0+2] + acc.w*asrc2[c0+3];
    float pd = acc.x*adst2[c0] + acc.y*adst2[c0+1] + acc.z*adst2[c0+2] + acc.w*adst2[c0+3];
    ps += __shfl_xor(ps, 1); ps += __shfl_xor(ps, 2);
    pd += __shfl_xor(pd, 1); pd += __shfl_xor(pd, 2);
    if (n < N){
        __half2 p0 = __floats2half2_rn(acc.x, acc.y);
        __half2 p1 = __floats2half2_rn(acc.z, acc.w);
        float2 ov;
        *(__half2*)&ov.x = p0; *(__half2*)&ov.y = p1;
        *(float2*)(h2h + (size_t)n*8 + cq*2) = ov;
        if (cq == 0){ as2[n] = ps; ad2[n] = pd; }
    }
}

// ---------------- layer-2 fused aggregation (half2 gather, 8 edges in flight) -> out ----------------
__global__ __launch_bounds__(256) void k_agg2(const __half2* __restrict__ h2h, const float* __restrict__ as2v,
                                              const float* __restrict__ ad2v,
                                              const int* __restrict__ offs, const int* __restrict__ esrc,
                                              const float* __restrict__ b2, float* __restrict__ out, int N){
    int n = blockIdx.x*4 + (threadIdx.x >> 6);
    if (n >= N) return;
    int l = threadIdx.x & 63;
    int e0 = offs[n], e1 = offs[n+1];
    float ad = ad2v[n];
    int eo = l >> 3, c2 = l & 7;
    float ax = 0.f, ay = 0.f, den = 0.f;
    for (int e = e0 + eo; e < e1; e += 8){
        int s = esrc[e];
        float w = __expf(lrelu(as2v[s] + ad));
        den += w;
        float2 f = __half22float2(h2h[(size_t)s*8 + c2]);
        ax += w * f.x; ay += w * f.y;
    }
    ax += __shfl_xor(ax, 8);  ay += __shfl_xor(ay, 8);  den += __shfl_xor(den, 8);
    ax += __shfl_xor(ax, 16); ay += __shfl_xor(ay, 16); den += __shfl_xor(den, 16);
    ax += __shfl_xor(ax, 32); ay += __shfl_xor(ay, 32); den += __shfl_xor(den, 32);
    if (eo == 0){
        float rd = 1.f / (den + 1e-16f);
        float2 bb = *(const float2*)(b2 + c2*2);
        float2 o = make_float2(ax*rd + bb.x, ay*rd + bb.y);
        *(float2*)(out + (size_t)n*16 + c2*2) = o;
    }
}

extern "C" void kernel_launch(void* const* d_in, const int* in_sizes, int n_in,
                              void* d_out, int out_size, void* d_ws, size_t ws_size,
                              hipStream_t stream){
    const float* x     = (const float*)d_in[0];
    const int*   ei    = (const int*)  d_in[1];
    const float* W1    = (const float*)d_in[2];
    const float* asrc1 = (const float*)d_in[3];
    const float* adst1 = (const float*)d_in[4];
    const float* b1    = (const float*)d_in[5];
    const float* W2    = (const float*)d_in[6];
    const float* asrc2 = (const float*)d_in[7];
    const float* adst2 = (const float*)d_in[8];
    const float* b2    = (const float*)d_in[9];
    float* out = (float*)d_out;

    const int N = in_sizes[0] / IN_CH;   // 100000
    const int E = in_sizes[1] / 2;       // 1600000
    const int ETOT = E + N;
    const int NBUCK = (N + NPB - 1) / NPB;   // 391

    char* p = (char*)d_ws;
    auto alloc = [&](size_t bytes) -> char* {
        char* r = p; p += (bytes + 255) & ~(size_t)255; return r;
    };
    __half2* h1h  = (__half2*)alloc((size_t)N * 64 * 4);
    __half2* hl2h = (__half2*)alloc((size_t)N * 64 * 4);
    unsigned char* h1q = (unsigned char*)alloc((size_t)N * 128);
    float2* asw  = (float2*)alloc((size_t)N * 8 * 8);
    float* ad1   = (float*)alloc((size_t)N * 8 * 4);
    __half2* h2h = (__half2*)alloc((size_t)N * 8 * 4);
    float* as2   = (float*)alloc((size_t)N * 4);
    float* ad2   = (float*)alloc((size_t)N * 4);
    int*   bcnt  = (int*)  alloc((size_t)MAXBUCK * 4);
    int*   boffs = (int*)  alloc((size_t)(MAXBUCK + 1) * 4);
    int*   bcur  = (int*)  alloc((size_t)MAXBUCK * 4);
    int*   offs  = (int*)  alloc((size_t)(N + 1) * 4);
    int*   esrc  = (int*)  alloc((size_t)ETOT * 4);
    int*   pbh   = (int*)  alloc((size_t)512 * MAXBUCK * 4);   // per-block bucket hist
    int2*  ebuck = (int2*)hl2h;   // aliases hl2h; k_csr done before k_agg1 writes it

    (void)hipMemsetAsync(bcnt, 0, (size_t)NBUCK * 4, stream);

    const int GPART = 512;
    const int epb = (E + GPART - 1) / GPART;

    k_bhist   <<<GPART, 256, 0, stream>>>(ei + E, E, NBUCK, epb, bcnt, pbh);
    k_bscan   <<<1,     512, 0, stream>>>(bcnt, NBUCK, E, boffs, bcur);
    k_bscatter<<<GPART, 256, 0, stream>>>(ei, E, NBUCK, epb, pbh, bcur, ebuck);
    k_csr     <<<NBUCK, 256, 0, stream>>>(ebuck, boffs, N, E, offs, esrc);

    const int NT = (N + 63) / 64;           // 1563 row tiles
    const int G1 = NT < 512 ? NT : 512;     // 2 blocks/CU, persistent W1
    k_gemm1  <<<G1, 256, 0, stream>>>(x, W1, (__half*)h1h, N, NT);
    k_alpha1 <<<(N * HEADS + 255) / 256, 256, 0, stream>>>(h1h, asrc1, adst1, asw, ad1, h1q, N);

    k_agg1   <<<(N + 7) / 8, 256, 0, stream>>>(h1q, asw, ad1, offs, esrc, b1, hl2h, N);

    k_gemm2  <<<(N + 63) / 64, 256, 0, stream>>>(hl2h, W2, asrc2, adst2, h2h, as2, ad2, N);
    k_agg2   <<<(N + 3) / 4, 256, 0, stream>>>(h2h, as2, ad2, offs, esrc, b2, out, N);
}

// Round 16
// 287.738 us; speedup vs baseline: 1.1320x; 1.0268x over previous
//
#include <hip/hip_runtime.h>
#include <hip/hip_fp16.h>
#include <math.h>

#define IN_CH 128
#define HEADS 8
#define HID 16
#define OUT_CH 16
#define NEG 0.2f
#define NPB 256          // nodes per bucket (>>8)
#define MAXBUCK 400
#define AST 136          // LDS k-stride in halfs (128 + 8 pad)

__device__ __forceinline__ float lrelu(float x){ return x > 0.f ? x : NEG * x; }
__device__ __forceinline__ float elu_fast(float x){ return x > 0.f ? x : __expf(x) - 1.f; }

typedef _Float16 half8 __attribute__((ext_vector_type(8)));
typedef float    f32x4 __attribute__((ext_vector_type(4)));

// ---------------- bucketed CSR build (bhist spills per-block hist for bscatter reuse) ----------------
__global__ __launch_bounds__(256) void k_bhist(const int* __restrict__ tgt, int E, int nbuck, int epb,
                                               int* __restrict__ bcnt, int* __restrict__ pbh){
    __shared__ int hist[MAXBUCK];
    int tid = threadIdx.x;
    for (int i = tid; i < nbuck; i += 256) hist[i] = 0;
    __syncthreads();
    int start = blockIdx.x * epb, end = min(start + epb, E);
    for (int e = start + tid; e < end; e += 256) atomicAdd(&hist[tgt[e] >> 8], 1);
    __syncthreads();
    int* row = pbh + (size_t)blockIdx.x * MAXBUCK;
    for (int i = tid; i < nbuck; i += 256){
        int h = hist[i];
        row[i] = h;
        if (h) atomicAdd(&bcnt[i], h);
    }
}

__global__ void k_bscan(const int* __restrict__ bcnt, int nbuck, int E,
                        int* __restrict__ boffs, int* __restrict__ bcur){
    __shared__ int s[512];
    int t = threadIdx.x;
    int v = (t < nbuck) ? bcnt[t] : 0;
    int orig = v;
    s[t] = v; __syncthreads();
    for (int off = 1; off < 512; off <<= 1){
        int u = (t >= off) ? s[t - off] : 0;
        __syncthreads();
        v += u; s[t] = v; __syncthreads();
    }
    if (t < nbuck){ boffs[t] = v - orig; bcur[t] = v - orig; }
    if (t == 0) boffs[nbuck] = E;
}

__global__ __launch_bounds__(256) void k_bscatter(const int* __restrict__ ei, int E, int nbuck, int epb,
                                                  const int* __restrict__ pbh,
                                                  int* __restrict__ bcur, int2* __restrict__ ebuck){
    __shared__ int hist[MAXBUCK];
    __shared__ int base[MAXBUCK];
    int tid = threadIdx.x;
    const int* row = pbh + (size_t)blockIdx.x * MAXBUCK;
    for (int i = tid; i < nbuck; i += 256){
        int h = row[i];
        base[i] = h ? atomicAdd(&bcur[i], h) : 0;
        hist[i] = 0;
    }
    __syncthreads();
    int start = blockIdx.x * epb, end = min(start + epb, E);
    for (int e = start + tid; e < end; e += 256){
        int s = ei[e], t = ei[E + e];
        int b = t >> 8;
        int r = atomicAdd(&hist[b], 1);
        ebuck[base[b] + r] = make_int2(s, t);
    }
}

__global__ __launch_bounds__(256) void k_csr(const int2* __restrict__ ebuck, const int* __restrict__ boffs,
                                             int N, int E,
                                             int* __restrict__ offs, int* __restrict__ esrc){
    __shared__ int cnt[256];
    __shared__ int sscan[256];
    __shared__ int wcur[256];
    int b = blockIdx.x;
    int tid = threadIdx.x;
    int n0 = b * 256;
    int nn = min(256, N - n0);
    cnt[tid] = (tid < nn) ? 1 : 0;
    __syncthreads();
    int e0 = boffs[b], e1 = boffs[b + 1];
    for (int e = e0 + tid; e < e1; e += 256) atomicAdd(&cnt[ebuck[e].y & 255], 1);
    __syncthreads();
    int v = cnt[tid], orig = v;
    sscan[tid] = v; __syncthreads();
    for (int off = 1; off < 256; off <<= 1){
        int u = (tid >= off) ? sscan[tid - off] : 0;
        __syncthreads();
        v += u; sscan[tid] = v; __syncthreads();
    }
    int excl = v - orig;
    int gbase = e0 + n0;
    if (tid < nn){
        offs[n0 + tid] = gbase + excl;
        esrc[gbase + excl] = n0 + tid;
    }
    wcur[tid] = excl + 1;
    __syncthreads();
    for (int e = e0 + tid; e < e1; e += 256){
        int2 p = ebuck[e];
        int r = atomicAdd(&wcur[p.y & 255], 1);
        esrc[gbase + r] = p.x;
    }
    if (b == 0 && tid == 0) offs[N] = E + N;
}

// ---------------- GEMM1 (MFMA fp16, persistent W1): h1 = x @ W1 -> fp16 [N][128] ----------------
__global__ __launch_bounds__(256) void k_gemm1(const float* __restrict__ x, const float* __restrict__ W1,
                                               __half* __restrict__ h1, int N, int NT){
    __shared__ _Float16 sB[128*AST];      // 34.8 KB (persistent)
    __shared__ _Float16 sA[2][64*AST];    // 2 x 17.4 KB double buffer
    int tid = threadIdx.x;
    for (int i = tid; i < 128*128; i += 256){
        int k = i >> 7, c = i & 127;
        sB[c*AST + k] = (_Float16)W1[i];
    }
    int wave = tid >> 6, lane = tid & 63;
    int m = lane & 15, quad = lane >> 4;
    int rbase = wave * 16;

    float4 vr[8];
    int tile = blockIdx.x;
    #pragma unroll
    for (int i = 0; i < 8; ++i){
        int q = i*256 + tid;
        int r = q >> 5, seg = q & 31;
        int row = tile*64 + r;
        vr[i] = make_float4(0.f,0.f,0.f,0.f);
        if (tile < NT && row < N) vr[i] = *(const float4*)(x + (size_t)row*128 + seg*4);
    }
    int b = 0;
    for (; tile < NT; tile += gridDim.x){
        #pragma unroll
        for (int i = 0; i < 8; ++i){
            int q = i*256 + tid;
            int r = q >> 5, seg = q & 31;
            _Float16* dst = &sA[b][r*AST + seg*4];
            dst[0]=(_Float16)vr[i].x; dst[1]=(_Float16)vr[i].y;
            dst[2]=(_Float16)vr[i].z; dst[3]=(_Float16)vr[i].w;
        }
        __syncthreads();
        int tn = tile + gridDim.x;
        #pragma unroll
        for (int i = 0; i < 8; ++i){
            int q = i*256 + tid;
            int r = q >> 5, seg = q & 31;
            int row = tn*64 + r;
            vr[i] = make_float4(0.f,0.f,0.f,0.f);
            if (tn < NT && row < N) vr[i] = *(const float4*)(x + (size_t)row*128 + seg*4);
        }
        f32x4 acc[8] = {};
        #pragma unroll
        for (int kc = 0; kc < 4; ++kc){
            int kb = kc*32 + quad*8;
            half8 a = *(half8*)(&sA[b][(rbase + m)*AST + kb]);
            #pragma unroll
            for (int t = 0; t < 8; ++t){
                half8 bb = *(half8*)(&sB[(t*16 + m)*AST + kb]);
                acc[t] = __builtin_amdgcn_mfma_f32_16x16x32_f16(a, bb, acc[t], 0, 0, 0);
            }
        }
        int row0 = tile*64;
        #pragma unroll
        for (int t = 0; t < 8; ++t){
            #pragma unroll
            for (int j = 0; j < 4; ++j){
                int r = row0 + rbase + quad*4 + j;
                if (r < N) h1[(size_t)r*128 + t*16 + m] = __float2half(acc[t][j]);
            }
        }
        b ^= 1;
    }
}

// ---------------- attention logits + per-(node,head) int8 quantization ----------------
struct H8 { __half2 v[8]; };

__global__ void k_alpha1(const __half2* __restrict__ h1h, const float* __restrict__ asrc, const float* __restrict__ adst,
                         float2* __restrict__ asw, float* __restrict__ ad1,
                         unsigned char* __restrict__ h1q, int N){
    int idx = blockIdx.x*blockDim.x + threadIdx.x;
    if (idx >= N*HEADS) return;
    int h = idx & 7;
    int n = idx >> 3;
    H8 blk = *(const H8*)(h1h + (size_t)n*64 + h*8);
    const float2* sp = (const float2*)(asrc + h*16);
    const float2* dp = (const float2*)(adst + h*16);
    float fv[16];
    float ss = 0.f, dd = 0.f;
    #pragma unroll
    for (int j = 0; j < 8; ++j){
        float2 v = __half22float2(blk.v[j]);
        fv[2*j] = v.x; fv[2*j+1] = v.y;
        float2 a = sp[j], b = dp[j];
        ss += v.x*a.x + v.y*a.y;
        dd += v.x*b.x + v.y*b.y;
    }
    float mx = 1e-12f;
    #pragma unroll
    for (int k = 0; k < 16; ++k) mx = fmaxf(mx, fabsf(fv[k]));
    float rs = 127.f / mx;
    unsigned int w[4];
    #pragma unroll
    for (int d = 0; d < 4; ++d){
        unsigned int b0 = (unsigned int)((int)rintf(fv[4*d+0]*rs) + 128);
        unsigned int b1 = (unsigned int)((int)rintf(fv[4*d+1]*rs) + 128);
        unsigned int b2 = (unsigned int)((int)rintf(fv[4*d+2]*rs) + 128);
        unsigned int b3 = (unsigned int)((int)rintf(fv[4*d+3]*rs) + 128);
        w[d] = b0 | (b1 << 8) | (b2 << 16) | (b3 << 24);
    }
    asw[idx] = make_float2(ss, mx * (1.f/127.f));
    ad1[idx] = dd;
    *(uint4*)(h1q + (size_t)idx*16) = make_uint4(w[0], w[1], w[2], w[3]);
}

// ---------------- layer-1 aggregation: int8 gather, depth-2 software pipeline ----------------
// 2 nodes/wave, 4 edge-slots x 8 head-lanes, 16 ch/lane. Pipeline: esrc for it+2 and
// dependent (asw,h1q) for it+1 issue before it's compute. Tail slots: w=0 + clamped idx.
__global__ __launch_bounds__(256) void k_agg1(const unsigned char* __restrict__ h1q, const float2* __restrict__ asw,
                                              const float* __restrict__ ad1,
                                              const int* __restrict__ offs, const int* __restrict__ esrc,
                                              const float* __restrict__ b1, __half2* __restrict__ hl2h, int N){
    int wv = threadIdx.x >> 6;
    int l  = threadIdx.x & 63;
    int nsub = l >> 5;
    int slot = (l >> 3) & 3;
    int c    = l & 7;
    int n = blockIdx.x*8 + wv*2 + nsub;
    bool alive = (n < N);
    float adc = 0.f;
    int e0 = 0, deg = 0;
    if (alive){
        adc = ad1[n*8 + c];
        e0 = offs[n];
        deg = offs[n+1] - e0;
    }
    int degmax = max(deg, __shfl_xor(deg, 32));
    int nit = (degmax + 7) >> 3;

    // pipeline prologue: stage A (esrc) for it=0,1; stage B (asw,h1q) for it=0
    int j0 = slot, j1 = 4 + slot;
    bool v0a = j0 < deg, v1a = j1 < deg;
    int s0 = esrc[e0 + (v0a ? j0 : 0)];
    int s1 = esrc[e0 + (v1a ? j1 : 0)];
    int j0b = 8 + slot, j1b = 12 + slot;
    bool v0b = j0b < deg, v1b = j1b < deg;
    int s0b = esrc[e0 + (v0b ? j0b : 0)];
    int s1b = esrc[e0 + (v1b ? j1b : 0)];
    float2 aw0 = asw[s0*8 + c];
    float2 aw1 = asw[s1*8 + c];
    uint4 q0 = *(const uint4*)(h1q + (size_t)s0*128 + c*16);
    uint4 q1 = *(const uint4*)(h1q + (size_t)s1*128 + c*16);

    float acc[16] = {};
    float den = 0.f;     // sum of w
    float dq  = 0.f;     // sum of w*scale
    for (int it = 0; it < nit; ++it){
        int ja = (it+2)*8 + slot, jb = ja + 4;
        bool nv0 = ja < deg, nv1 = jb < deg;
        int ns0 = esrc[e0 + (nv0 ? ja : 0)];
        int ns1 = esrc[e0 + (nv1 ? jb : 0)];
        float2 naw0 = asw[s0b*8 + c];
        float2 naw1 = asw[s1b*8 + c];
        uint4 nq0 = *(const uint4*)(h1q + (size_t)s0b*128 + c*16);
        uint4 nq1 = *(const uint4*)(h1q + (size_t)s1b*128 + c*16);

        float w0 = v0a ? __expf(lrelu(aw0.x + adc)) : 0.f;
        float w1 = v1a ? __expf(lrelu(aw1.x + adc)) : 0.f;
        float wq0 = w0 * aw0.y;
        float wq1 = w1 * aw1.y;
        den += w0 + w1;
        dq  += wq0 + wq1;
        const unsigned int* u0 = (const unsigned int*)&q0;
        const unsigned int* u1 = (const unsigned int*)&q1;
        #pragma unroll
        for (int d = 0; d < 4; ++d){
            unsigned int a = u0[d], b = u1[d];
            acc[4*d+0] += wq0 * (float)(a & 255u);
            acc[4*d+1] += wq0 * (float)((a >> 8) & 255u);
            acc[4*d+2] += wq0 * (float)((a >> 16) & 255u);
            acc[4*d+3] += wq0 * (float)(a >> 24);
            acc[4*d+0] += wq1 * (float)(b & 255u);
            acc[4*d+1] += wq1 * (float)((b >> 8) & 255u);
            acc[4*d+2] += wq1 * (float)((b >> 16) & 255u);
            acc[4*d+3] += wq1 * (float)(b >> 24);
        }
        v0a = v0b; v1a = v1b;
        aw0 = naw0; aw1 = naw1; q0 = nq0; q1 = nq1;
        v0b = nv0; v1b = nv1; s0b = ns0; s1b = ns1;
    }
    den += __shfl_xor(den, 8);  den += __shfl_xor(den, 16);
    dq  += __shfl_xor(dq, 8);   dq  += __shfl_xor(dq, 16);
    #pragma unroll
    for (int k = 0; k < 16; ++k){
        acc[k] += __shfl_xor(acc[k], 8);
        acc[k] += __shfl_xor(acc[k], 16);
    }
    if (!alive) return;
    float rd = 1.f / (den + 1e-16f);
    float bias128 = 128.f * dq;
    float sel0, sel1, sel2, sel3;
    {
        float a0 = (slot & 1) ? acc[4]  : acc[0];
        float b0 = (slot & 1) ? acc[12] : acc[8];
        sel0 = (slot & 2) ? b0 : a0;
        float a1 = (slot & 1) ? acc[5]  : acc[1];
        float b1v = (slot & 1) ? acc[13] : acc[9];
        sel1 = (slot & 2) ? b1v : a1;
        float a2 = (slot & 1) ? acc[6]  : acc[2];
        float b2v = (slot & 1) ? acc[14] : acc[10];
        sel2 = (slot & 2) ? b2v : a2;
        float a3 = (slot & 1) ? acc[7]  : acc[3];
        float b3v = (slot & 1) ? acc[15] : acc[11];
        sel3 = (slot & 2) ? b3v : a3;
    }
    float4 b4 = *(const float4*)(b1 + c*16 + slot*4);
    float v0 = elu_fast((sel0 - bias128)*rd + b4.x);
    float v1 = elu_fast((sel1 - bias128)*rd + b4.y);
    float v2 = elu_fast((sel2 - bias128)*rd + b4.z);
    float v3 = elu_fast((sel3 - bias128)*rd + b4.w);
    __half2 q0h = __floats2half2_rn(v0, v1);
    __half2 q1h = __floats2half2_rn(v2, v3);
    float2 ov;
    *(__half2*)&ov.x = q0h; *(__half2*)&ov.y = q1h;
    *(float2*)(hl2h + (size_t)n*64 + c*8 + slot*2) = ov;
}

// ---------------- GEMM2: h2 = hl2 @ W2 -> fp16 + fused alpha2 ----------------
#define FMA4(acc, a, b) { acc.x += (a)*(b).x; acc.y += (a)*(b).y; acc.z += (a)*(b).z; acc.w += (a)*(b).w; }

__global__ __launch_bounds__(256) void k_gemm2(const __half2* __restrict__ hl2h, const float* __restrict__ W2,
                                               const float* __restrict__ asrc2, const float* __restrict__ adst2,
                                               __half2* __restrict__ h2h, float* __restrict__ as2, float* __restrict__ ad2,
                                               int N){
    __shared__ float sX[64*132];
    __shared__ float sW2[128*16];
    int tid = threadIdx.x;
    for (int i = tid; i < 128*16; i += 256) sW2[i] = W2[i];
    int row0 = blockIdx.x * 64;
    #pragma unroll
    for (int i = 0; i < 4; ++i){
        int q = i*256 + tid;
        int r = q >> 4, seg = q & 15;
        float4 raw = make_float4(0.f,0.f,0.f,0.f);
        if (row0 + r < N) raw = ((const float4*)(hl2h + (size_t)(row0+r)*64))[seg];
        const __half2* hp = (const __half2*)&raw;
        float* dst = &sX[r*132 + seg*8];
        #pragma unroll
        for (int j = 0; j < 4; ++j){
            float2 f = __half22float2(hp[j]);
            dst[2*j] = f.x; dst[2*j+1] = f.y;
        }
    }
    __syncthreads();
    int nd = tid >> 2;
    int cq = tid & 3, c0 = cq*4;
    int n = row0 + nd;
    float4 acc = make_float4(0.f,0.f,0.f,0.f);
    #pragma unroll 4
    for (int k4 = 0; k4 < 32; ++k4){
        float4 a  = *(const float4*)(&sX[nd*132 + k4*4]);
        float4 w0 = *(const float4*)(&sW2[(k4*4+0)*16 + c0]);
        float4 w1 = *(const float4*)(&sW2[(k4*4+1)*16 + c0]);
        float4 w2 = *(const float4*)(&sW2[(k4*4+2)*16 + c0]);
        float4 w3 = *(const float4*)(&sW2[(k4*4+3)*16 + c0]);
        FMA4(acc, a.x, w0); FMA4(acc, a.y, w1); FMA4(acc, a.z, w2); FMA4(acc, a.w, w3);
    }
    float ps = acc.x*asrc2[c0] + acc.y*asrc2[c0+1] + acc.z*asrc2[c0+2] + acc.w*asrc2[c0+3];
    float pd = acc.x*adst2[c0] + acc.y*adst2[c0+1] + acc.z*adst2[c0+2] + acc.w*adst2[c0+3];
    ps += __shfl_xor(ps, 1); ps += __shfl_xor(ps, 2);
    pd += __shfl_xor(pd, 1); pd += __shfl_xor(pd, 2);
    if (n < N){
        __half2 p0 = __floats2half2_rn(acc.x, acc.y);
        __half2 p1 = __floats2half2_rn(acc.z, acc.w);
        float2 ov;
        *(__half2*)&ov.x = p0; *(__half2*)&ov.y = p1;
        *(float2*)(h2h + (size_t)n*8 + cq*2) = ov;
        if (cq == 0){ as2[n] = ps; ad2[n] = pd; }
    }
}

// ---------------- layer-2 aggregation: flat 4-deep predicated unroll (32 edges in flight) ----
// 1 node/wave, 8 edge-slots x 8 lanes, 2 ch/lane. All 4 esrc loads (j, j+8, j+16, j+24)
// issue back-to-back, then 8 independent dependent loads -> 2 latency hops total instead
// of ~3 serial rounds. Tail loop handles rare deg>32. Clamped-index no-op predication.
__global__ __launch_bounds__(256) void k_agg2(const __half2* __restrict__ h2h, const float* __restrict__ as2v,
                                              const float* __restrict__ ad2v,
                                              const int* __restrict__ offs, const int* __restrict__ esrc,
                                              const float* __restrict__ b2, float* __restrict__ out, int N){
    int n = blockIdx.x*4 + (threadIdx.x >> 6);
    if (n >= N) return;
    int l = threadIdx.x & 63;
    int eo = l >> 3, c2 = l & 7;
    int e0 = offs[n], e1 = offs[n+1];
    int deg = e1 - e0;
    float ad = ad2v[n];

    bool v0 = eo < deg, v1 = eo+8 < deg, v2 = eo+16 < deg, v3 = eo+24 < deg;
    int s0 = esrc[e0 + (v0 ? eo      : 0)];
    int s1 = esrc[e0 + (v1 ? eo + 8  : 0)];
    int s2 = esrc[e0 + (v2 ? eo + 16 : 0)];
    int s3 = esrc[e0 + (v3 ? eo + 24 : 0)];
    float a0 = as2v[s0], a1 = as2v[s1], a2 = as2v[s2], a3 = as2v[s3];
    float2 f0 = __half22float2(h2h[(size_t)s0*8 + c2]);
    float2 f1 = __half22float2(h2h[(size_t)s1*8 + c2]);
    float2 f2 = __half22float2(h2h[(size_t)s2*8 + c2]);
    float2 f3 = __half22float2(h2h[(size_t)s3*8 + c2]);
    float w0 = v0 ? __expf(lrelu(a0 + ad)) : 0.f;
    float w1 = v1 ? __expf(lrelu(a1 + ad)) : 0.f;
    float w2 = v2 ? __expf(lrelu(a2 + ad)) : 0.f;
    float w3 = v3 ? __expf(lrelu(a3 + ad)) : 0.f;
    float den = w0 + w1 + w2 + w3;
    float ax = w0*f0.x + w1*f1.x + w2*f2.x + w3*f3.x;
    float ay = w0*f0.y + w1*f1.y + w2*f2.y + w3*f3.y;

    // rare tail: deg > 32
    for (int e = e0 + 32 + eo; e < e1; e += 8){
        int s = esrc[e];
        float w = __expf(lrelu(as2v[s] + ad));
        den += w;
        float2 f = __half22float2(h2h[(size_t)s*8 + c2]);
        ax += w * f.x; ay += w * f.y;
    }
    ax += __shfl_xor(ax, 8);  ay += __shfl_xor(ay, 8);  den += __shfl_xor(den, 8);
    ax += __shfl_xor(ax, 16); ay += __shfl_xor(ay, 16); den += __shfl_xor(den, 16);
    ax += __shfl_xor(ax, 32); ay += __shfl_xor(ay, 32); den += __shfl_xor(den, 32);
    if (eo == 0){
        float rd = 1.f / (den + 1e-16f);
        float2 bb = *(const float2*)(b2 + c2*2);
        float2 o = make_float2(ax*rd + bb.x, ay*rd + bb.y);
        *(float2*)(out + (size_t)n*16 + c2*2) = o;
    }
}

extern "C" void kernel_launch(void* const* d_in, const int* in_sizes, int n_in,
                              void* d_out, int out_size, void* d_ws, size_t ws_size,
                              hipStream_t stream){
    const float* x     = (const float*)d_in[0];
    const int*   ei    = (const int*)  d_in[1];
    const float* W1    = (const float*)d_in[2];
    const float* asrc1 = (const float*)d_in[3];
    const float* adst1 = (const float*)d_in[4];
    const float* b1    = (const float*)d_in[5];
    const float* W2    = (const float*)d_in[6];
    const float* asrc2 = (const float*)d_in[7];
    const float* adst2 = (const float*)d_in[8];
    const float* b2    = (const float*)d_in[9];
    float* out = (float*)d_out;

    const int N = in_sizes[0] / IN_CH;   // 100000
    const int E = in_sizes[1] / 2;       // 1600000
    const int ETOT = E + N;
    const int NBUCK = (N + NPB - 1) / NPB;   // 391

    char* p = (char*)d_ws;
    auto alloc = [&](size_t bytes) -> char* {
        char* r = p; p += (bytes + 255) & ~(size_t)255; return r;
    };
    __half2* h1h  = (__half2*)alloc((size_t)N * 64 * 4);
    __half2* hl2h = (__half2*)alloc((size_t)N * 64 * 4);
    unsigned char* h1q = (unsigned char*)alloc((size_t)N * 128);
    float2* asw  = (float2*)alloc((size_t)N * 8 * 8);
    float* ad1   = (float*)alloc((size_t)N * 8 * 4);
    __half2* h2h = (__half2*)alloc((size_t)N * 8 * 4);
    float* as2   = (float*)alloc((size_t)N * 4);
    float* ad2   = (float*)alloc((size_t)N * 4);
    int*   bcnt  = (int*)  alloc((size_t)MAXBUCK * 4);
    int*   boffs = (int*)  alloc((size_t)(MAXBUCK + 1) * 4);
    int*   bcur  = (int*)  alloc((size_t)MAXBUCK * 4);
    int*   offs  = (int*)  alloc((size_t)(N + 1) * 4);
    int*   esrc  = (int*)  alloc((size_t)ETOT * 4);
    int*   pbh   = (int*)  alloc((size_t)512 * MAXBUCK * 4);   // per-block bucket hist
    int2*  ebuck = (int2*)hl2h;   // aliases hl2h; k_csr done before k_agg1 writes it

    (void)hipMemsetAsync(bcnt, 0, (size_t)NBUCK * 4, stream);

    const int GPART = 512;
    const int epb = (E + GPART - 1) / GPART;

    k_bhist   <<<GPART, 256, 0, stream>>>(ei + E, E, NBUCK, epb, bcnt, pbh);
    k_bscan   <<<1,     512, 0, stream>>>(bcnt, NBUCK, E, boffs, bcur);
    k_bscatter<<<GPART, 256, 0, stream>>>(ei, E, NBUCK, epb, pbh, bcur, ebuck);
    k_csr     <<<NBUCK, 256, 0, stream>>>(ebuck, boffs, N, E, offs, esrc);

    const int NT = (N + 63) / 64;           // 1563 row tiles
    const int G1 = NT < 512 ? NT : 512;     // 2 blocks/CU, persistent W1
    k_gemm1  <<<G1, 256, 0, stream>>>(x, W1, (__half*)h1h, N, NT);
    k_alpha1 <<<(N * HEADS + 255) / 256, 256, 0, stream>>>(h1h, asrc1, adst1, asw, ad1, h1q, N);

    k_agg1   <<<(N + 7) / 8, 256, 0, stream>>>(h1q, asw, ad1, offs, esrc, b1, hl2h, N);

    k_gemm2  <<<(N + 63) / 64, 256, 0, stream>>>(hl2h, W2, asrc2, adst2, h2h, as2, ad2, N);
    k_agg2   <<<(N + 3) / 4, 256, 0, stream>>>(h2h, as2, ad2, offs, esrc, b2, out, N);
}